// Round 1
// baseline (2082.422 us; speedup 1.0000x reference)
//
#include <hip/hip_runtime.h>
#include <math.h>

#define BS 256
#define MM 128
#define NN 1024
#define ITERS 100
#define ALPHA 0.1f

typedef _Float16 half8 __attribute__((ext_vector_type(8)));
typedef _Float16 half4 __attribute__((ext_vector_type(4)));
typedef _Float16 half2v __attribute__((ext_vector_type(2)));
typedef float f32x4 __attribute__((ext_vector_type(4)));

// Exact butterfly add via DPP (VALU pipe, no LDS). Controls used:
//   0xB1 = quad_perm [1,0,3,2]  (xor 1)
//   0x4E = quad_perm [2,3,0,1]  (xor 2)
//   0x141 = row_half_mirror     (xor 7 within 8 -> cross-quad)
//   0x140 = row_mirror          (xor 15 within 16 -> cross-8)
template <int CTRL>
__device__ __forceinline__ float dpp_add(float x) {
  int xi = __builtin_bit_cast(int, x);
  int r = __builtin_amdgcn_update_dpp(xi, xi, CTRL, 0xf, 0xf, true);
  return x + __builtin_bit_cast(float, r);
}

// ---------------------------------------------------------------------------
// AAT: C[b] = A[b] * A[b]^T (128x128) via split-fp16 MFMA (hi/lo decomposition
// gives fp32-equivalent accuracy: a = hi + lo with |lo| <= 2^-11|a|, and we
// keep hi*hi + hi*lo + lo*hi, dropping only the 2^-22 lo*lo term).
// One block per batch, 512 threads = 8 waves. Also emits the fp16 AT copy
// (identical conversion path to the previous kernel).
#define AST 129
__global__ __launch_bounds__(512) void k_aat(const float* __restrict__ A,
                                             float* __restrict__ C,
                                             _Float16* __restrict__ ATh) {
  __shared__ float As[64 * AST];                          // [k][m] fp32, for ATh emission
  __shared__ __align__(16) _Float16 Thi[8][2][64][8];     // frag-order hi tiles (16 KB)
  __shared__ __align__(16) _Float16 Tlo[8][2][64][8];     // frag-order lo tiles (16 KB)
  int b = blockIdx.x;
  int tid = threadIdx.x;
  const float* Ab = A + (size_t)b * MM * NN;
  float* Cb = C + (size_t)b * MM * MM;
  _Float16* ATb = ATh + (size_t)b * NN * MM;

  int lane = tid & 63;
  int w = tid >> 6;      // wave 0..7
  int wr = w & 3;        // row-pair index: row strips {2wr, 2wr+1}
  int wc = w >> 2;       // col-half index: col strips {4wc .. 4wc+3}

  f32x4 acc[2][4];
#pragma unroll
  for (int i = 0; i < 2; ++i)
#pragma unroll
    for (int j = 0; j < 4; ++j) acc[i][j] = (f32x4){0.f, 0.f, 0.f, 0.f};

  for (int t = 0; t < 16; ++t) {
    int k0 = t * 64;
    // ---- stage: global float4 -> fp32 [k][m] tile + split fp16 frag tiles
#pragma unroll
    for (int s = 0; s < 4; ++s) {
      int c = tid + s * 512;          // 0..2047
      int m = c >> 4;                 // 0..127
      int q = c & 15;                 // float4 index in row
      int kl = q * 4;                 // 0..60 (local k)
      float4 v = *(const float4*)&Ab[(size_t)m * NN + k0 + kl];
      As[(kl + 0) * AST + m] = v.x;
      As[(kl + 1) * AST + m] = v.y;
      As[(kl + 2) * AST + m] = v.z;
      As[(kl + 3) * AST + m] = v.w;
      _Float16 h0 = (_Float16)v.x, h1 = (_Float16)v.y;
      _Float16 h2 = (_Float16)v.z, h3 = (_Float16)v.w;
      half4 hv = {h0, h1, h2, h3};
      half4 lv = {(_Float16)(v.x - (float)h0), (_Float16)(v.y - (float)h1),
                  (_Float16)(v.z - (float)h2), (_Float16)(v.w - (float)h3)};
      int strip = m >> 4;                         // 0..7
      int kc = kl >> 5;                           // 0..1
      int ln = (m & 15) + (((kl & 31) >> 3) << 4);  // frag lane
      int j0 = kl & 7;                            // 0 or 4
      *(half4*)&Thi[strip][kc][ln][j0] = hv;
      *(half4*)&Tlo[strip][kc][ln][j0] = lv;
    }
    __syncthreads();
    // ---- emit fp16 AT k-slice (same conversion as before -> k_main numerics unchanged)
#pragma unroll
    for (int s = 0; s < 8; ++s) {
      int idx = tid + s * 512;        // 0..4095
      int nl = idx >> 6;              // 0..63
      int mp = idx & 63;              // m-pair
      half2v hv;
      hv[0] = (_Float16)As[nl * AST + 2 * mp];
      hv[1] = (_Float16)As[nl * AST + 2 * mp + 1];
      *(half2v*)&ATb[(size_t)(k0 + nl) * MM + 2 * mp] = hv;
    }
    // ---- MFMA: 2x4 tiles of 16x16 per wave, K=64 this pass
#pragma unroll
    for (int kc = 0; kc < 2; ++kc) {
      half8 ahi[2], alo[2], bhi[4], blo[4];
#pragma unroll
      for (int i = 0; i < 2; ++i) {
        ahi[i] = *(const half8*)&Thi[2 * wr + i][kc][lane][0];
        alo[i] = *(const half8*)&Tlo[2 * wr + i][kc][lane][0];
      }
#pragma unroll
      for (int j = 0; j < 4; ++j) {
        bhi[j] = *(const half8*)&Thi[4 * wc + j][kc][lane][0];
        blo[j] = *(const half8*)&Tlo[4 * wc + j][kc][lane][0];
      }
#pragma unroll
      for (int i = 0; i < 2; ++i)
#pragma unroll
        for (int j = 0; j < 4; ++j) {
          acc[i][j] = __builtin_amdgcn_mfma_f32_16x16x32_f16(ahi[i], bhi[j],
                                                             acc[i][j], 0, 0, 0);
          acc[i][j] = __builtin_amdgcn_mfma_f32_16x16x32_f16(ahi[i], blo[j],
                                                             acc[i][j], 0, 0, 0);
          acc[i][j] = __builtin_amdgcn_mfma_f32_16x16x32_f16(alo[i], bhi[j],
                                                             acc[i][j], 0, 0, 0);
        }
    }
    __syncthreads();
  }
  // ---- write C: D layout col=lane&15, row=4*(lane>>4)+reg
  int rbase = 4 * (lane >> 4);
  int cbase = lane & 15;
#pragma unroll
  for (int i = 0; i < 2; ++i)
#pragma unroll
    for (int j = 0; j < 4; ++j) {
      int r0 = (2 * wr + i) * 16 + rbase;
      int c0 = (4 * wc + j) * 16 + cbase;
#pragma unroll
      for (int r = 0; r < 4; ++r)
        Cb[(size_t)(r0 + r) * MM + c0] = acc[i][j][r];
    }
}

// ---------------------------------------------------------------------------
// In-place Gauss-Jordan inverse of SPD 128x128. 512 threads; stride-129 LDS;
// merged pivot-scale into the update -> 2 barriers/step. (unchanged)
#define IST 129
__global__ __launch_bounds__(512) void k_inv(float* __restrict__ G) {
  __shared__ float Msh[MM * IST];
  int b = blockIdx.x;
  int tid = threadIdx.x;
  float* Gb = G + (size_t)b * MM * MM;
#pragma unroll
  for (int s = 0; s < 8; ++s) {
    int idx = (tid + s * 512) * 4;
    float4 v = *(const float4*)&Gb[idx];
    int i = idx >> 7, j = idx & 127;
    Msh[i * IST + j + 0] = v.x;
    Msh[i * IST + j + 1] = v.y;
    Msh[i * IST + j + 2] = v.z;
    Msh[i * IST + j + 3] = v.w;
  }
  __syncthreads();
  int j = tid & 127;
  int i0 = (tid >> 7) * 32;   // this thread owns rows i0..i0+31, column j
  for (int k = 0; k < MM; ++k) {
    float p = 1.0f / Msh[k * IST + k];
    float mkj = Msh[k * IST + j];
    float fik[32];
#pragma unroll
    for (int ii = 0; ii < 32; ++ii) fik[ii] = Msh[(i0 + ii) * IST + k];
    __syncthreads();
    float pmkj = p * mkj;
#pragma unroll
    for (int ii = 0; ii < 32; ++ii) {
      int i = i0 + ii;
      float nij;
      if (i == k)
        nij = (j == k) ? p : pmkj;          // row k scaled; diag = 1/pivot
      else if (j == k)
        nij = -p * fik[ii];                 // col k
      else
        nij = Msh[i * IST + j] - fik[ii] * pmkj;
      Msh[i * IST + j] = nij;
    }
    __syncthreads();
  }
#pragma unroll
  for (int s = 0; s < 8; ++s) {
    int idx = (tid + s * 512) * 4;
    int i = idx >> 7, jj = idx & 127;
    float4 v;
    v.x = Msh[i * IST + jj + 0];
    v.y = Msh[i * IST + jj + 1];
    v.z = Msh[i * IST + jj + 2];
    v.w = Msh[i * IST + jj + 3];
    *(float4*)&Gb[idx] = v;
  }
}

// ---------------------------------------------------------------------------
// Persistent solver: one block per batch, 1024 threads (16 waves).
// This round: all 16-lane/8-lane shuffle reductions moved from the LDS pipe
// (ds_swizzle) to VALU DPP butterflies; z state moved to registers (the
// column->group mapping is iteration-invariant and all 16 lanes already
// compute the update redundantly); td/di packed into one float2 LDS read.
#define TRP 132
__global__ __attribute__((amdgpu_waves_per_eu(4, 4)))
__launch_bounds__(1024) void k_main(
    const _Float16* __restrict__ AT, const float* __restrict__ G,
    const float* __restrict__ bvec, const float* __restrict__ D1,
    const float* __restrict__ D2, float* __restrict__ out) {
  __shared__ __align__(16) _Float16 AL[512 * MM];   // 131 KB
  __shared__ float z_sh[NN];                        // output staging (last iter)
  __shared__ float2 tdi_sh[NN];                     // {alpha*|D1|, 1/(1+2a D2^2)}
  __shared__ float b_sh[MM];
  __shared__ __align__(16) _Float16 s_h[MM];
  __shared__ __align__(16) _Float16 u_h[MM];
  __shared__ __align__(16) float t_redW[16][TRP];

  int b = blockIdx.x;
  int tid = threadIdx.x;
  const _Float16* ATb = AT + (size_t)b * NN * MM;
  const float* Gb = G + (size_t)b * MM * MM;

  // ---- G fragment: 8 threads per row, 16 elems each, packed fp16 (8 VGPRs)
  int sub = tid & 7, r = tid >> 3;
  float ghf[8];
#pragma unroll
  for (int s = 0; s < 4; ++s) {
    float4 v = *(const float4*)&Gb[(size_t)r * MM + 16 * sub + 4 * s];
    half2v h0; h0[0] = (_Float16)v.x; h0[1] = (_Float16)v.y;
    half2v h1; h1[0] = (_Float16)v.z; h1[1] = (_Float16)v.w;
    ghf[2 * s + 0] = __builtin_bit_cast(float, h0);
    ghf[2 * s + 1] = __builtin_bit_cast(float, h1);
  }
#pragma unroll
  for (int s = 0; s < 8; ++s) asm volatile("" : "+v"(ghf[s]));
  {
    float d1 = D1[(size_t)b * NN + tid];
    float d2 = D2[(size_t)b * NN + tid];
    float2 td2;
    td2.x = ALPHA * fabsf(d1);
    td2.y = 1.0f / (1.0f + 2.0f * ALPHA * d2 * d2);
    tdi_sh[tid] = td2;
    z_sh[tid] = 0.0f;
  }
  if (tid < MM) {
    float bb = bvec[(size_t)b * MM + tid];
    b_sh[tid] = bb;
    s_h[tid] = (_Float16)(-bb);   // s_0 = A*y_0 - b = -b
  }

  int l16 = tid & 15;          // lane in 16-group
  int grp4 = (tid >> 4) & 3;   // group within wave
  int w = tid >> 6;            // wave 0..15
  int mbase = 8 * l16;

  // ---- LDS cols: AL col = 32*w + j  <->  n = 64*w + 32 + j  (j = 0..31)
#pragma unroll
  for (int i = 0; i < 8; ++i) {
    int c = tid + 1024 * i;          // 16B chunk id, 0..8191
    int col = c >> 4;                // 0..511 (16 chunks per col)
    int m8 = (c & 15) * 8;           // half-index within col
    int n = 32 * (col >> 5) + 32 + col;
    *(half8*)&AL[col * MM + m8] = *(const half8*)&ATb[(size_t)n * MM + m8];
  }

  // ---- register cols: n = 64*w + 16 + 4*j + grp4, j = 0..3 (16 VGPRs, pinned)
  float af0[4], af1[4], af2[4], af3[4];
#pragma unroll
  for (int j = 0; j < 4; ++j) {
    float4 v =
        *(const float4*)&ATb[(size_t)(64 * w + 16 + 4 * j + grp4) * MM + mbase];
    af0[j] = v.x; af1[j] = v.y; af2[j] = v.z; af3[j] = v.w;
  }
#pragma unroll
  for (int j = 0; j < 4; ++j) {
    asm volatile("" : "+v"(af0[j]));
    asm volatile("" : "+v"(af1[j]));
    asm volatile("" : "+v"(af2[j]));
    asm volatile("" : "+v"(af3[j]));
  }

  // ---- z state in registers, replicated across the 16-lane group.
  // Order: [0..3] reg cols, [4..11] LDS cols, [12..15] streamed cols.
  float zz[16];
#pragma unroll
  for (int j = 0; j < 16; ++j) zz[j] = 0.0f;

  __syncthreads();

  for (int it = 0; it < ITERS; ++it) {
    bool last = (it == ITERS - 1);

    // ---- issue streamed-col loads early (cols 64w + 4j + grp4, j=0..3)
    float4 st[4];
#pragma unroll
    for (int j = 0; j < 4; ++j)
      st[j] = *(const float4*)&ATb[(size_t)(64 * w + 4 * j + grp4) * MM + mbase];

    // ---- u = G * s  (8 threads per row, packed fp16 dot; DPP 8-lane reduce)
    {
      int j0 = 16 * sub;
      half8 sA = *(const half8*)&s_h[j0];
      half8 sB = *(const half8*)&s_h[j0 + 8];
      float up = 0.0f;
      up = __builtin_amdgcn_fdot2(__builtin_bit_cast(half2v, ghf[0]),
                                  __builtin_shufflevector(sA, sA, 0, 1), up, false);
      up = __builtin_amdgcn_fdot2(__builtin_bit_cast(half2v, ghf[1]),
                                  __builtin_shufflevector(sA, sA, 2, 3), up, false);
      up = __builtin_amdgcn_fdot2(__builtin_bit_cast(half2v, ghf[2]),
                                  __builtin_shufflevector(sA, sA, 4, 5), up, false);
      up = __builtin_amdgcn_fdot2(__builtin_bit_cast(half2v, ghf[3]),
                                  __builtin_shufflevector(sA, sA, 6, 7), up, false);
      up = __builtin_amdgcn_fdot2(__builtin_bit_cast(half2v, ghf[4]),
                                  __builtin_shufflevector(sB, sB, 0, 1), up, false);
      up = __builtin_amdgcn_fdot2(__builtin_bit_cast(half2v, ghf[5]),
                                  __builtin_shufflevector(sB, sB, 2, 3), up, false);
      up = __builtin_amdgcn_fdot2(__builtin_bit_cast(half2v, ghf[6]),
                                  __builtin_shufflevector(sB, sB, 4, 5), up, false);
      up = __builtin_amdgcn_fdot2(__builtin_bit_cast(half2v, ghf[7]),
                                  __builtin_shufflevector(sB, sB, 6, 7), up, false);
      up = dpp_add<0xB1>(up);    // quad_perm xor1
      up = dpp_add<0x4E>(up);    // quad_perm xor2
      up = dpp_add<0x141>(up);   // row_half_mirror (cross-quad within 8)
      if (sub == 0) u_h[r] = (_Float16)up;
    }
    __syncthreads();
    half8 uu = *(const half8*)&u_h[mbase];
    half2v u0 = __builtin_shufflevector(uu, uu, 0, 1);
    half2v u1 = __builtin_shufflevector(uu, uu, 2, 3);
    half2v u2 = __builtin_shufflevector(uu, uu, 4, 5);
    half2v u3 = __builtin_shufflevector(uu, uu, 6, 7);
    float t[8];
#pragma unroll
    for (int k = 0; k < 8; ++k) t[k] = 0.0f;

    auto colstep = [&](half2v a0, half2v a1, half2v a2, half2v a3, int n,
                       float& zn) {
      float cp = 0.0f;
      cp = __builtin_amdgcn_fdot2(a0, u0, cp, false);
      cp = __builtin_amdgcn_fdot2(a1, u1, cp, false);
      cp = __builtin_amdgcn_fdot2(a2, u2, cp, false);
      cp = __builtin_amdgcn_fdot2(a3, u3, cp, false);
      cp = dpp_add<0xB1>(cp);    // xor1
      cp = dpp_add<0x4E>(cp);    // xor2
      cp = dpp_add<0x141>(cp);   // half_mirror: 8-sum in all 8 lanes
      cp = dpp_add<0x140>(cp);   // mirror: 16-sum in all 16 lanes
      float2 tdi = tdi_sh[n];    // single b64 broadcast read
      float td = tdi.x, di = tdi.y;
      float zv = zn;
      float xm = zv - td, xp = zv + td;
      float xh = xm > 0.0f ? xm * di : (xp < 0.0f ? xp * di : 0.0f);
      if (!last) {
        float z1 = xh - cp;                     // z_{i+1}
        float xm1 = z1 - td, xp1 = z1 + td;
        float xh1 = xm1 > 0.0f ? xm1 * di : (xp1 < 0.0f ? xp1 * di : 0.0f);
        float y = 2.0f * xh1 - z1;              // y_{i+1}
        zn = z1;                                // register, all lanes identical
        t[0] += (float)a0[0] * y; t[1] += (float)a0[1] * y;
        t[2] += (float)a1[0] * y; t[3] += (float)a1[1] * y;
        t[4] += (float)a2[0] * y; t[5] += (float)a2[1] * y;
        t[6] += (float)a3[0] * y; t[7] += (float)a3[1] * y;
      } else {
        float y = 2.0f * xh - zv;               // y_99 from z_99
        if (l16 == 0) z_sh[n] = y - cp;         // x_99 (output)
      }
    };

    // register cols first, then LDS cols, then streamed (loads have arrived)
#pragma unroll
    for (int j = 0; j < 4; ++j)
      colstep(__builtin_bit_cast(half2v, af0[j]),
              __builtin_bit_cast(half2v, af1[j]),
              __builtin_bit_cast(half2v, af2[j]),
              __builtin_bit_cast(half2v, af3[j]), 64 * w + 16 + 4 * j + grp4,
              zz[j]);
#pragma unroll
    for (int j = 0; j < 8; ++j) {
      half8 av = *(const half8*)&AL[(32 * w + 4 * j + grp4) * MM + mbase];
      colstep(__builtin_shufflevector(av, av, 0, 1),
              __builtin_shufflevector(av, av, 2, 3),
              __builtin_shufflevector(av, av, 4, 5),
              __builtin_shufflevector(av, av, 6, 7), 64 * w + 32 + 4 * j + grp4,
              zz[4 + j]);
    }
#pragma unroll
    for (int j = 0; j < 4; ++j) {
      colstep(__builtin_bit_cast(half2v, st[j].x),
              __builtin_bit_cast(half2v, st[j].y),
              __builtin_bit_cast(half2v, st[j].z),
              __builtin_bit_cast(half2v, st[j].w), 64 * w + 4 * j + grp4,
              zz[12 + j]);
    }

    if (!last) {
      // ---- in-wave cross-group reduce, then 16-wave LDS reduce
#pragma unroll
      for (int k = 0; k < 8; ++k) {
        t[k] += __shfl_xor(t[k], 16);
        t[k] += __shfl_xor(t[k], 32);
      }
      if (grp4 == 0) {
        float4 ta; ta.x = t[0]; ta.y = t[1]; ta.z = t[2]; ta.w = t[3];
        float4 tb; tb.x = t[4]; tb.y = t[5]; tb.z = t[6]; tb.w = t[7];
        *(float4*)&t_redW[w][mbase] = ta;
        *(float4*)&t_redW[w][mbase + 4] = tb;
      }
      __syncthreads();
      if (tid < MM) {
        float ssum = -b_sh[tid];
#pragma unroll
        for (int h = 0; h < 16; ++h) ssum += t_redW[h][tid];
        s_h[tid] = (_Float16)ssum;   // s = A*y - b for next pass's u
      }
      __syncthreads();
    }
  }

  __syncthreads();
  out[(size_t)b * NN + tid] = z_sh[tid];
}

// ---------------------------------------------------------------------------
extern "C" void kernel_launch(void* const* d_in, const int* in_sizes, int n_in,
                              void* d_out, int out_size, void* d_ws, size_t ws_size,
                              hipStream_t stream) {
  const float* A  = (const float*)d_in[0];  // (BS, M, N)
  const float* bv = (const float*)d_in[1];  // (BS, M)
  const float* D1 = (const float*)d_in[2];  // (BS, N)
  const float* D2 = (const float*)d_in[3];  // (BS, N)
  float* out = (float*)d_out;               // (BS, N)

  _Float16* ATh = (_Float16*)d_ws;                              // 67 MB
  float* G = (float*)((char*)d_ws + (size_t)BS * NN * MM * 2);  // 16.7 MB

  k_aat<<<BS, 512, 0, stream>>>(A, G, ATh);
  k_inv<<<BS, 512, 0, stream>>>(G);
  k_main<<<BS, 1024, 0, stream>>>(ATh, G, bv, D1, D2, out);
}

// Round 2
// 1185.770 us; speedup vs baseline: 1.7562x; 1.7562x over previous
//
#include <hip/hip_runtime.h>
#include <math.h>

#define BS 256
#define MM 128
#define NN 1024
#define ITERS 100
#define ALPHA 0.1f

typedef _Float16 half8 __attribute__((ext_vector_type(8)));
typedef _Float16 half4 __attribute__((ext_vector_type(4)));
typedef _Float16 half2v __attribute__((ext_vector_type(2)));
typedef float f32x4 __attribute__((ext_vector_type(4)));

// Exact butterfly add via DPP (VALU pipe, no LDS). Controls used:
//   0xB1 = quad_perm [1,0,3,2]  (xor 1)
//   0x4E = quad_perm [2,3,0,1]  (xor 2)
//   0x141 = row_half_mirror     (xor within 8 -> cross-quad)
//   0x140 = row_mirror          (xor within 16 -> cross-8)
template <int CTRL>
__device__ __forceinline__ float dpp_add(float x) {
  int xi = __builtin_bit_cast(int, x);
  int r = __builtin_amdgcn_update_dpp(xi, xi, CTRL, 0xf, 0xf, true);
  return x + __builtin_bit_cast(float, r);
}

// ---------------------------------------------------------------------------
// AAT: C[b] = A[b] * A[b]^T (128x128) via split-fp16 MFMA (hi/lo decomposition
// gives fp32-equivalent accuracy). One block per batch, 512 threads = 8 waves.
// Also emits the fp16 AT copy (identical conversion path to round 0).
#define AST 129
__global__ __launch_bounds__(512) void k_aat(const float* __restrict__ A,
                                             float* __restrict__ C,
                                             _Float16* __restrict__ ATh) {
  __shared__ float As[64 * AST];                          // [k][m] fp32, for ATh emission
  __shared__ __align__(16) _Float16 Thi[8][2][64][8];     // frag-order hi tiles (16 KB)
  __shared__ __align__(16) _Float16 Tlo[8][2][64][8];     // frag-order lo tiles (16 KB)
  int b = blockIdx.x;
  int tid = threadIdx.x;
  const float* Ab = A + (size_t)b * MM * NN;
  float* Cb = C + (size_t)b * MM * MM;
  _Float16* ATb = ATh + (size_t)b * NN * MM;

  int lane = tid & 63;
  int w = tid >> 6;      // wave 0..7
  int wr = w & 3;        // row-pair index: row strips {2wr, 2wr+1}
  int wc = w >> 2;       // col-half index: col strips {4wc .. 4wc+3}

  f32x4 acc[2][4];
#pragma unroll
  for (int i = 0; i < 2; ++i)
#pragma unroll
    for (int j = 0; j < 4; ++j) acc[i][j] = (f32x4){0.f, 0.f, 0.f, 0.f};

  for (int t = 0; t < 16; ++t) {
    int k0 = t * 64;
    // ---- stage: global float4 -> fp32 [k][m] tile + split fp16 frag tiles
#pragma unroll
    for (int s = 0; s < 4; ++s) {
      int c = tid + s * 512;          // 0..2047
      int m = c >> 4;                 // 0..127
      int q = c & 15;                 // float4 index in row
      int kl = q * 4;                 // 0..60 (local k)
      float4 v = *(const float4*)&Ab[(size_t)m * NN + k0 + kl];
      As[(kl + 0) * AST + m] = v.x;
      As[(kl + 1) * AST + m] = v.y;
      As[(kl + 2) * AST + m] = v.z;
      As[(kl + 3) * AST + m] = v.w;
      _Float16 h0 = (_Float16)v.x, h1 = (_Float16)v.y;
      _Float16 h2 = (_Float16)v.z, h3 = (_Float16)v.w;
      half4 hv = {h0, h1, h2, h3};
      half4 lv = {(_Float16)(v.x - (float)h0), (_Float16)(v.y - (float)h1),
                  (_Float16)(v.z - (float)h2), (_Float16)(v.w - (float)h3)};
      int strip = m >> 4;                         // 0..7
      int kc = kl >> 5;                           // 0..1
      int ln = (m & 15) + (((kl & 31) >> 3) << 4);  // frag lane
      int j0 = kl & 7;                            // 0 or 4
      *(half4*)&Thi[strip][kc][ln][j0] = hv;
      *(half4*)&Tlo[strip][kc][ln][j0] = lv;
    }
    __syncthreads();
    // ---- emit fp16 AT k-slice (same conversion as round 0)
#pragma unroll
    for (int s = 0; s < 8; ++s) {
      int idx = tid + s * 512;        // 0..4095
      int nl = idx >> 6;              // 0..63
      int mp = idx & 63;              // m-pair
      half2v hv;
      hv[0] = (_Float16)As[nl * AST + 2 * mp];
      hv[1] = (_Float16)As[nl * AST + 2 * mp + 1];
      *(half2v*)&ATb[(size_t)(k0 + nl) * MM + 2 * mp] = hv;
    }
    // ---- MFMA: 2x4 tiles of 16x16 per wave, K=64 this pass
#pragma unroll
    for (int kc = 0; kc < 2; ++kc) {
      half8 ahi[2], alo[2], bhi[4], blo[4];
#pragma unroll
      for (int i = 0; i < 2; ++i) {
        ahi[i] = *(const half8*)&Thi[2 * wr + i][kc][lane][0];
        alo[i] = *(const half8*)&Tlo[2 * wr + i][kc][lane][0];
      }
#pragma unroll
      for (int j = 0; j < 4; ++j) {
        bhi[j] = *(const half8*)&Thi[4 * wc + j][kc][lane][0];
        blo[j] = *(const half8*)&Tlo[4 * wc + j][kc][lane][0];
      }
#pragma unroll
      for (int i = 0; i < 2; ++i)
#pragma unroll
        for (int j = 0; j < 4; ++j) {
          acc[i][j] = __builtin_amdgcn_mfma_f32_16x16x32_f16(ahi[i], bhi[j],
                                                             acc[i][j], 0, 0, 0);
          acc[i][j] = __builtin_amdgcn_mfma_f32_16x16x32_f16(ahi[i], blo[j],
                                                             acc[i][j], 0, 0, 0);
          acc[i][j] = __builtin_amdgcn_mfma_f32_16x16x32_f16(alo[i], bhi[j],
                                                             acc[i][j], 0, 0, 0);
        }
    }
    __syncthreads();
  }
  // ---- write C: D layout col=lane&15, row=4*(lane>>4)+reg
  int rbase = 4 * (lane >> 4);
  int cbase = lane & 15;
#pragma unroll
  for (int i = 0; i < 2; ++i)
#pragma unroll
    for (int j = 0; j < 4; ++j) {
      int r0 = (2 * wr + i) * 16 + rbase;
      int c0 = (4 * wc + j) * 16 + cbase;
#pragma unroll
      for (int r = 0; r < 4; ++r)
        Cb[(size_t)(r0 + r) * MM + c0] = acc[i][j][r];
    }
}

// ---------------------------------------------------------------------------
// In-place Gauss-Jordan inverse of SPD 128x128. (unchanged)
#define IST 129
__global__ __launch_bounds__(512) void k_inv(float* __restrict__ G) {
  __shared__ float Msh[MM * IST];
  int b = blockIdx.x;
  int tid = threadIdx.x;
  float* Gb = G + (size_t)b * MM * MM;
#pragma unroll
  for (int s = 0; s < 8; ++s) {
    int idx = (tid + s * 512) * 4;
    float4 v = *(const float4*)&Gb[idx];
    int i = idx >> 7, j = idx & 127;
    Msh[i * IST + j + 0] = v.x;
    Msh[i * IST + j + 1] = v.y;
    Msh[i * IST + j + 2] = v.z;
    Msh[i * IST + j + 3] = v.w;
  }
  __syncthreads();
  int j = tid & 127;
  int i0 = (tid >> 7) * 32;   // this thread owns rows i0..i0+31, column j
  for (int k = 0; k < MM; ++k) {
    float p = 1.0f / Msh[k * IST + k];
    float mkj = Msh[k * IST + j];
    float fik[32];
#pragma unroll
    for (int ii = 0; ii < 32; ++ii) fik[ii] = Msh[(i0 + ii) * IST + k];
    __syncthreads();
    float pmkj = p * mkj;
#pragma unroll
    for (int ii = 0; ii < 32; ++ii) {
      int i = i0 + ii;
      float nij;
      if (i == k)
        nij = (j == k) ? p : pmkj;          // row k scaled; diag = 1/pivot
      else if (j == k)
        nij = -p * fik[ii];                 // col k
      else
        nij = Msh[i * IST + j] - fik[ii] * pmkj;
      Msh[i * IST + j] = nij;
    }
    __syncthreads();
  }
#pragma unroll
  for (int s = 0; s < 8; ++s) {
    int idx = (tid + s * 512) * 4;
    int i = idx >> 7, jj = idx & 127;
    float4 v;
    v.x = Msh[i * IST + jj + 0];
    v.y = Msh[i * IST + jj + 1];
    v.z = Msh[i * IST + jj + 2];
    v.w = Msh[i * IST + jj + 3];
    *(float4*)&Gb[idx] = v;
  }
}

// ---------------------------------------------------------------------------
// Persistent solver: one block per batch, 1024 threads (16 waves).
// REGISTER ENVELOPE IS HARD: the allocator targets 64 VGPRs here; any extra
// live state spills to scratch, whose L2 pollution evicts the streamed cols
// (round-1 post-mortem: FETCH 54.9MB -> 2.96GB). z stays in LDS.
// This round vs round 0: all 8/16-lane reductions moved from the LDS pipe
// (ds_swizzle) to VALU DPP butterflies; td/di packed into one float2 read.
#define TRP 132
__global__ __attribute__((amdgpu_waves_per_eu(4, 4)))
__launch_bounds__(1024) void k_main(
    const _Float16* __restrict__ AT, const float* __restrict__ G,
    const float* __restrict__ bvec, const float* __restrict__ D1,
    const float* __restrict__ D2, float* __restrict__ out) {
  __shared__ __align__(16) _Float16 AL[512 * MM];   // 131 KB
  __shared__ float z_sh[NN];
  __shared__ float2 tdi_sh[NN];                     // {alpha*|D1|, 1/(1+2a D2^2)}
  __shared__ float b_sh[MM];
  __shared__ __align__(16) _Float16 s_h[MM];
  __shared__ __align__(16) _Float16 u_h[MM];
  __shared__ __align__(16) float t_redW[16][TRP];

  int b = blockIdx.x;
  int tid = threadIdx.x;
  const _Float16* ATb = AT + (size_t)b * NN * MM;
  const float* Gb = G + (size_t)b * MM * MM;

  // ---- G fragment: 8 threads per row, 16 elems each, packed fp16 (8 VGPRs)
  int sub = tid & 7, r = tid >> 3;
  float ghf[8];
#pragma unroll
  for (int s = 0; s < 4; ++s) {
    float4 v = *(const float4*)&Gb[(size_t)r * MM + 16 * sub + 4 * s];
    half2v h0; h0[0] = (_Float16)v.x; h0[1] = (_Float16)v.y;
    half2v h1; h1[0] = (_Float16)v.z; h1[1] = (_Float16)v.w;
    ghf[2 * s + 0] = __builtin_bit_cast(float, h0);
    ghf[2 * s + 1] = __builtin_bit_cast(float, h1);
  }
#pragma unroll
  for (int s = 0; s < 8; ++s) asm volatile("" : "+v"(ghf[s]));
  {
    float d1 = D1[(size_t)b * NN + tid];
    float d2 = D2[(size_t)b * NN + tid];
    float2 td2;
    td2.x = ALPHA * fabsf(d1);
    td2.y = 1.0f / (1.0f + 2.0f * ALPHA * d2 * d2);
    tdi_sh[tid] = td2;
    z_sh[tid] = 0.0f;
  }
  if (tid < MM) {
    float bb = bvec[(size_t)b * MM + tid];
    b_sh[tid] = bb;
    s_h[tid] = (_Float16)(-bb);   // s_0 = A*y_0 - b = -b
  }

  int l16 = tid & 15;          // lane in 16-group
  int grp4 = (tid >> 4) & 3;   // group within wave
  int w = tid >> 6;            // wave 0..15
  int mbase = 8 * l16;

  // ---- LDS cols: AL col = 32*w + j  <->  n = 64*w + 32 + j  (j = 0..31)
#pragma unroll
  for (int i = 0; i < 8; ++i) {
    int c = tid + 1024 * i;          // 16B chunk id, 0..8191
    int col = c >> 4;                // 0..511 (16 chunks per col)
    int m8 = (c & 15) * 8;           // half-index within col
    int n = 32 * (col >> 5) + 32 + col;
    *(half8*)&AL[col * MM + m8] = *(const half8*)&ATb[(size_t)n * MM + m8];
  }

  // ---- register cols: n = 64*w + 16 + 4*j + grp4, j = 0..3 (16 VGPRs, pinned)
  float af0[4], af1[4], af2[4], af3[4];
#pragma unroll
  for (int j = 0; j < 4; ++j) {
    float4 v =
        *(const float4*)&ATb[(size_t)(64 * w + 16 + 4 * j + grp4) * MM + mbase];
    af0[j] = v.x; af1[j] = v.y; af2[j] = v.z; af3[j] = v.w;
  }
#pragma unroll
  for (int j = 0; j < 4; ++j) {
    asm volatile("" : "+v"(af0[j]));
    asm volatile("" : "+v"(af1[j]));
    asm volatile("" : "+v"(af2[j]));
    asm volatile("" : "+v"(af3[j]));
  }
  __syncthreads();

  for (int it = 0; it < ITERS; ++it) {
    bool last = (it == ITERS - 1);

    // ---- issue streamed-col loads early (cols 64w + 4j + grp4, j=0..3)
    float4 st[4];
#pragma unroll
    for (int j = 0; j < 4; ++j)
      st[j] = *(const float4*)&ATb[(size_t)(64 * w + 4 * j + grp4) * MM + mbase];

    // ---- u = G * s  (8 threads per row, packed fp16 dot; DPP 8-lane reduce)
    {
      int j0 = 16 * sub;
      half8 sA = *(const half8*)&s_h[j0];
      half8 sB = *(const half8*)&s_h[j0 + 8];
      float up = 0.0f;
      up = __builtin_amdgcn_fdot2(__builtin_bit_cast(half2v, ghf[0]),
                                  __builtin_shufflevector(sA, sA, 0, 1), up, false);
      up = __builtin_amdgcn_fdot2(__builtin_bit_cast(half2v, ghf[1]),
                                  __builtin_shufflevector(sA, sA, 2, 3), up, false);
      up = __builtin_amdgcn_fdot2(__builtin_bit_cast(half2v, ghf[2]),
                                  __builtin_shufflevector(sA, sA, 4, 5), up, false);
      up = __builtin_amdgcn_fdot2(__builtin_bit_cast(half2v, ghf[3]),
                                  __builtin_shufflevector(sA, sA, 6, 7), up, false);
      up = __builtin_amdgcn_fdot2(__builtin_bit_cast(half2v, ghf[4]),
                                  __builtin_shufflevector(sB, sB, 0, 1), up, false);
      up = __builtin_amdgcn_fdot2(__builtin_bit_cast(half2v, ghf[5]),
                                  __builtin_shufflevector(sB, sB, 2, 3), up, false);
      up = __builtin_amdgcn_fdot2(__builtin_bit_cast(half2v, ghf[6]),
                                  __builtin_shufflevector(sB, sB, 4, 5), up, false);
      up = __builtin_amdgcn_fdot2(__builtin_bit_cast(half2v, ghf[7]),
                                  __builtin_shufflevector(sB, sB, 6, 7), up, false);
      up = dpp_add<0xB1>(up);    // quad_perm xor1
      up = dpp_add<0x4E>(up);    // quad_perm xor2
      up = dpp_add<0x141>(up);   // row_half_mirror (cross-quad within 8)
      if (sub == 0) u_h[r] = (_Float16)up;
    }
    __syncthreads();
    half8 uu = *(const half8*)&u_h[mbase];
    half2v u0 = __builtin_shufflevector(uu, uu, 0, 1);
    half2v u1 = __builtin_shufflevector(uu, uu, 2, 3);
    half2v u2 = __builtin_shufflevector(uu, uu, 4, 5);
    half2v u3 = __builtin_shufflevector(uu, uu, 6, 7);
    float t[8];
#pragma unroll
    for (int k = 0; k < 8; ++k) t[k] = 0.0f;

    auto colstep = [&](half2v a0, half2v a1, half2v a2, half2v a3, int n) {
      float cp = 0.0f;
      cp = __builtin_amdgcn_fdot2(a0, u0, cp, false);
      cp = __builtin_amdgcn_fdot2(a1, u1, cp, false);
      cp = __builtin_amdgcn_fdot2(a2, u2, cp, false);
      cp = __builtin_amdgcn_fdot2(a3, u3, cp, false);
      cp = dpp_add<0xB1>(cp);    // xor1
      cp = dpp_add<0x4E>(cp);    // xor2
      cp = dpp_add<0x141>(cp);   // half_mirror: 8-sum in all 8 lanes
      cp = dpp_add<0x140>(cp);   // mirror: 16-sum in all 16 lanes
      float2 tdi = tdi_sh[n];    // single b64 broadcast read
      float td = tdi.x, di = tdi.y;
      float zn = z_sh[n];        // broadcast
      float xm = zn - td, xp = zn + td;
      float xh = xm > 0.0f ? xm * di : (xp < 0.0f ? xp * di : 0.0f);
      if (!last) {
        float z1 = xh - cp;                     // z_{i+1}
        float xm1 = z1 - td, xp1 = z1 + td;
        float xh1 = xm1 > 0.0f ? xm1 * di : (xp1 < 0.0f ? xp1 * di : 0.0f);
        float y = 2.0f * xh1 - z1;              // y_{i+1}
        if (l16 == 0) z_sh[n] = z1;
        t[0] += (float)a0[0] * y; t[1] += (float)a0[1] * y;
        t[2] += (float)a1[0] * y; t[3] += (float)a1[1] * y;
        t[4] += (float)a2[0] * y; t[5] += (float)a2[1] * y;
        t[6] += (float)a3[0] * y; t[7] += (float)a3[1] * y;
      } else {
        float y = 2.0f * xh - zn;               // y_99 from z_99
        if (l16 == 0) z_sh[n] = y - cp;         // x_99 (output)
      }
    };

    // register cols first, then LDS cols, then streamed (loads have arrived)
#pragma unroll
    for (int j = 0; j < 4; ++j)
      colstep(__builtin_bit_cast(half2v, af0[j]),
              __builtin_bit_cast(half2v, af1[j]),
              __builtin_bit_cast(half2v, af2[j]),
              __builtin_bit_cast(half2v, af3[j]), 64 * w + 16 + 4 * j + grp4);
#pragma unroll
    for (int j = 0; j < 8; ++j) {
      half8 av = *(const half8*)&AL[(32 * w + 4 * j + grp4) * MM + mbase];
      colstep(__builtin_shufflevector(av, av, 0, 1),
              __builtin_shufflevector(av, av, 2, 3),
              __builtin_shufflevector(av, av, 4, 5),
              __builtin_shufflevector(av, av, 6, 7), 64 * w + 32 + 4 * j + grp4);
    }
#pragma unroll
    for (int j = 0; j < 4; ++j) {
      colstep(__builtin_bit_cast(half2v, st[j].x),
              __builtin_bit_cast(half2v, st[j].y),
              __builtin_bit_cast(half2v, st[j].z),
              __builtin_bit_cast(half2v, st[j].w), 64 * w + 4 * j + grp4);
    }

    if (!last) {
      // ---- in-wave cross-group reduce, then 16-wave LDS reduce
#pragma unroll
      for (int k = 0; k < 8; ++k) {
        t[k] += __shfl_xor(t[k], 16);
        t[k] += __shfl_xor(t[k], 32);
      }
      if (grp4 == 0) {
        float4 ta; ta.x = t[0]; ta.y = t[1]; ta.z = t[2]; ta.w = t[3];
        float4 tb; tb.x = t[4]; tb.y = t[5]; tb.z = t[6]; tb.w = t[7];
        *(float4*)&t_redW[w][mbase] = ta;
        *(float4*)&t_redW[w][mbase + 4] = tb;
      }
      __syncthreads();
      if (tid < MM) {
        float ssum = -b_sh[tid];
#pragma unroll
        for (int h = 0; h < 16; ++h) ssum += t_redW[h][tid];
        s_h[tid] = (_Float16)ssum;   // s = A*y - b for next pass's u
      }
      __syncthreads();
    }
  }

  __syncthreads();
  out[(size_t)b * NN + tid] = z_sh[tid];
}

// ---------------------------------------------------------------------------
extern "C" void kernel_launch(void* const* d_in, const int* in_sizes, int n_in,
                              void* d_out, int out_size, void* d_ws, size_t ws_size,
                              hipStream_t stream) {
  const float* A  = (const float*)d_in[0];  // (BS, M, N)
  const float* bv = (const float*)d_in[1];  // (BS, M)
  const float* D1 = (const float*)d_in[2];  // (BS, N)
  const float* D2 = (const float*)d_in[3];  // (BS, N)
  float* out = (float*)d_out;               // (BS, N)

  _Float16* ATh = (_Float16*)d_ws;                              // 67 MB
  float* G = (float*)((char*)d_ws + (size_t)BS * NN * MM * 2);  // 16.7 MB

  k_aat<<<BS, 512, 0, stream>>>(A, G, ATh);
  k_inv<<<BS, 512, 0, stream>>>(G);
  k_main<<<BS, 1024, 0, stream>>>(ATh, G, bv, D1, D2, out);
}

// Round 3
// 922.414 us; speedup vs baseline: 2.2576x; 1.2855x over previous
//
#include <hip/hip_runtime.h>
#include <math.h>

#define BS 256
#define MM 128
#define NN 1024
#define ITERS 100
#define ALPHA 0.1f

typedef _Float16 half8 __attribute__((ext_vector_type(8)));
typedef _Float16 half4 __attribute__((ext_vector_type(4)));
typedef _Float16 half2v __attribute__((ext_vector_type(2)));
typedef float f32x4 __attribute__((ext_vector_type(4)));

// Exact butterfly add via DPP (VALU pipe, no LDS). Controls:
//   0xB1 quad_perm xor1 | 0x4E quad_perm xor2 | 0x141 row_half_mirror (xor7
//   within 8) | 0x140 row_mirror (xor15 within 16) | 0x128 row_ror:8
//   ((l+8)%16 == l^8 -> xor8 within each 16-lane row)
template <int CTRL>
__device__ __forceinline__ float dpp_add(float x) {
  int xi = __builtin_bit_cast(int, x);
  int r = __builtin_amdgcn_update_dpp(xi, xi, CTRL, 0xf, 0xf, true);
  return x + __builtin_bit_cast(float, r);
}

// ---------------------------------------------------------------------------
// AAT: C[b] = A[b] * A[b]^T (128x128) via split-fp16 MFMA (hi/lo decomposition
// gives fp32-equivalent accuracy). One block per batch, 512 threads = 8 waves.
// Also emits the fp16 AT copy. (unchanged from round 2)
#define AST 129
__global__ __launch_bounds__(512) void k_aat(const float* __restrict__ A,
                                             float* __restrict__ C,
                                             _Float16* __restrict__ ATh) {
  __shared__ float As[64 * AST];
  __shared__ __align__(16) _Float16 Thi[8][2][64][8];
  __shared__ __align__(16) _Float16 Tlo[8][2][64][8];
  int b = blockIdx.x;
  int tid = threadIdx.x;
  const float* Ab = A + (size_t)b * MM * NN;
  float* Cb = C + (size_t)b * MM * MM;
  _Float16* ATb = ATh + (size_t)b * NN * MM;

  int lane = tid & 63;
  int w = tid >> 6;
  int wr = w & 3;
  int wc = w >> 2;

  f32x4 acc[2][4];
#pragma unroll
  for (int i = 0; i < 2; ++i)
#pragma unroll
    for (int j = 0; j < 4; ++j) acc[i][j] = (f32x4){0.f, 0.f, 0.f, 0.f};

  for (int t = 0; t < 16; ++t) {
    int k0 = t * 64;
#pragma unroll
    for (int s = 0; s < 4; ++s) {
      int c = tid + s * 512;
      int m = c >> 4;
      int q = c & 15;
      int kl = q * 4;
      float4 v = *(const float4*)&Ab[(size_t)m * NN + k0 + kl];
      As[(kl + 0) * AST + m] = v.x;
      As[(kl + 1) * AST + m] = v.y;
      As[(kl + 2) * AST + m] = v.z;
      As[(kl + 3) * AST + m] = v.w;
      _Float16 h0 = (_Float16)v.x, h1 = (_Float16)v.y;
      _Float16 h2 = (_Float16)v.z, h3 = (_Float16)v.w;
      half4 hv = {h0, h1, h2, h3};
      half4 lv = {(_Float16)(v.x - (float)h0), (_Float16)(v.y - (float)h1),
                  (_Float16)(v.z - (float)h2), (_Float16)(v.w - (float)h3)};
      int strip = m >> 4;
      int kc = kl >> 5;
      int ln = (m & 15) + (((kl & 31) >> 3) << 4);
      int j0 = kl & 7;
      *(half4*)&Thi[strip][kc][ln][j0] = hv;
      *(half4*)&Tlo[strip][kc][ln][j0] = lv;
    }
    __syncthreads();
#pragma unroll
    for (int s = 0; s < 8; ++s) {
      int idx = tid + s * 512;
      int nl = idx >> 6;
      int mp = idx & 63;
      half2v hv;
      hv[0] = (_Float16)As[nl * AST + 2 * mp];
      hv[1] = (_Float16)As[nl * AST + 2 * mp + 1];
      *(half2v*)&ATb[(size_t)(k0 + nl) * MM + 2 * mp] = hv;
    }
#pragma unroll
    for (int kc = 0; kc < 2; ++kc) {
      half8 ahi[2], alo[2], bhi[4], blo[4];
#pragma unroll
      for (int i = 0; i < 2; ++i) {
        ahi[i] = *(const half8*)&Thi[2 * wr + i][kc][lane][0];
        alo[i] = *(const half8*)&Tlo[2 * wr + i][kc][lane][0];
      }
#pragma unroll
      for (int j = 0; j < 4; ++j) {
        bhi[j] = *(const half8*)&Thi[4 * wc + j][kc][lane][0];
        blo[j] = *(const half8*)&Tlo[4 * wc + j][kc][lane][0];
      }
#pragma unroll
      for (int i = 0; i < 2; ++i)
#pragma unroll
        for (int j = 0; j < 4; ++j) {
          acc[i][j] = __builtin_amdgcn_mfma_f32_16x16x32_f16(ahi[i], bhi[j],
                                                             acc[i][j], 0, 0, 0);
          acc[i][j] = __builtin_amdgcn_mfma_f32_16x16x32_f16(ahi[i], blo[j],
                                                             acc[i][j], 0, 0, 0);
          acc[i][j] = __builtin_amdgcn_mfma_f32_16x16x32_f16(alo[i], bhi[j],
                                                             acc[i][j], 0, 0, 0);
        }
    }
    __syncthreads();
  }
  int rbase = 4 * (lane >> 4);
  int cbase = lane & 15;
#pragma unroll
  for (int i = 0; i < 2; ++i)
#pragma unroll
    for (int j = 0; j < 4; ++j) {
      int r0 = (2 * wr + i) * 16 + rbase;
      int c0 = (4 * wc + j) * 16 + cbase;
#pragma unroll
      for (int r = 0; r < 4; ++r)
        Cb[(size_t)(r0 + r) * MM + c0] = acc[i][j][r];
    }
}

// ---------------------------------------------------------------------------
// In-place Gauss-Jordan inverse of SPD 128x128. (unchanged)
#define IST 129
__global__ __launch_bounds__(512) void k_inv(float* __restrict__ G) {
  __shared__ float Msh[MM * IST];
  int b = blockIdx.x;
  int tid = threadIdx.x;
  float* Gb = G + (size_t)b * MM * MM;
#pragma unroll
  for (int s = 0; s < 8; ++s) {
    int idx = (tid + s * 512) * 4;
    float4 v = *(const float4*)&Gb[idx];
    int i = idx >> 7, j = idx & 127;
    Msh[i * IST + j + 0] = v.x;
    Msh[i * IST + j + 1] = v.y;
    Msh[i * IST + j + 2] = v.z;
    Msh[i * IST + j + 3] = v.w;
  }
  __syncthreads();
  int j = tid & 127;
  int i0 = (tid >> 7) * 32;
  for (int k = 0; k < MM; ++k) {
    float p = 1.0f / Msh[k * IST + k];
    float mkj = Msh[k * IST + j];
    float fik[32];
#pragma unroll
    for (int ii = 0; ii < 32; ++ii) fik[ii] = Msh[(i0 + ii) * IST + k];
    __syncthreads();
    float pmkj = p * mkj;
#pragma unroll
    for (int ii = 0; ii < 32; ++ii) {
      int i = i0 + ii;
      float nij;
      if (i == k)
        nij = (j == k) ? p : pmkj;
      else if (j == k)
        nij = -p * fik[ii];
      else
        nij = Msh[i * IST + j] - fik[ii] * pmkj;
      Msh[i * IST + j] = nij;
    }
    __syncthreads();
  }
#pragma unroll
  for (int s = 0; s < 8; ++s) {
    int idx = (tid + s * 512) * 4;
    int i = idx >> 7, jj = idx & 127;
    float4 v;
    v.x = Msh[i * IST + jj + 0];
    v.y = Msh[i * IST + jj + 1];
    v.z = Msh[i * IST + jj + 2];
    v.w = Msh[i * IST + jj + 3];
    *(float4*)&Gb[idx] = v;
  }
}

// ---------------------------------------------------------------------------
// Persistent solver: one block per batch, 1024 threads (16 waves).
// Round-3 restructure: 8-lane column groups (16 m-elems/lane), so
//   - soft-threshold redundancy 16x -> 8x
//   - cp reduce: 3 DPP steps x 8 cols (was 4 x 16)
//   - z lives in registers (passed BY VALUE through colstep -- round-1's
//     scratch explosion came from a by-reference array param, rule #20)
//   - t-accum via v_fma_mix_f32 (f16-src FMA, no cvt)
//   - t cross-group reduce: xor8 = DPP row_ror:8, xor32 = shfl; xor16
//     eliminated by writing 32 partial rows (2 reducer waves absorb it)
//   - AL 16B parity-swizzled so paired groups hit disjoint bank sets
#define TRP 132
__global__ __attribute__((amdgpu_waves_per_eu(4, 4)))
__launch_bounds__(1024) void k_main(
    const _Float16* __restrict__ AT, const float* __restrict__ G,
    const float* __restrict__ bvec, const float* __restrict__ D1,
    const float* __restrict__ D2, float* __restrict__ out) {
  __shared__ __align__(16) _Float16 AL[512 * MM];   // 131 KB
  __shared__ float z_sh[NN];                        // output staging only
  __shared__ float2 tdi_sh[NN];
  __shared__ float b_sh[MM];
  __shared__ __align__(16) _Float16 s_h[MM];
  __shared__ __align__(16) _Float16 u_h[MM];
  __shared__ __align__(16) float t_redW[32][TRP];   // 32 partial rows

  int b = blockIdx.x;
  int tid = threadIdx.x;
  const _Float16* ATb = AT + (size_t)b * NN * MM;
  const float* Gb = G + (size_t)b * MM * MM;

  // ---- G fragment: 8 threads per row, 16 elems each, packed fp16 (8 VGPRs)
  int sub = tid & 7, r = tid >> 3;
  float ghf[8];
#pragma unroll
  for (int s = 0; s < 4; ++s) {
    float4 v = *(const float4*)&Gb[(size_t)r * MM + 16 * sub + 4 * s];
    half2v h0; h0[0] = (_Float16)v.x; h0[1] = (_Float16)v.y;
    half2v h1; h1[0] = (_Float16)v.z; h1[1] = (_Float16)v.w;
    ghf[2 * s + 0] = __builtin_bit_cast(float, h0);
    ghf[2 * s + 1] = __builtin_bit_cast(float, h1);
  }
#pragma unroll
  for (int s = 0; s < 8; ++s) asm volatile("" : "+v"(ghf[s]));
  {
    float d1 = D1[(size_t)b * NN + tid];
    float d2 = D2[(size_t)b * NN + tid];
    float2 td2;
    td2.x = ALPHA * fabsf(d1);
    td2.y = 1.0f / (1.0f + 2.0f * ALPHA * d2 * d2);
    tdi_sh[tid] = td2;
  }
  if (tid < MM) {
    float bb = bvec[(size_t)b * MM + tid];
    b_sh[tid] = bb;
    s_h[tid] = (_Float16)(-bb);   // s_0 = A*y_0 - b = -b
  }

  int l8 = tid & 7;            // lane in 8-group
  int g = (tid >> 3) & 7;      // group within wave (8 groups)
  int w = tid >> 6;            // wave 0..15
  int mb = 16 * l8;            // m-slice base (16 elems/lane)
  int alsw = (g & 1) * 8;      // AL parity swizzle (matches col&1 = g&1)

  // ---- LDS cols: AL col c holds n = 64*(c>>5)+32+(c&31); 16B parity swizzle
#pragma unroll
  for (int i = 0; i < 8; ++i) {
    int c = tid + 1024 * i;
    int col = c >> 4;
    int m8 = (c & 15) * 8;
    int n = 32 * (col >> 5) + 32 + col;
    int phys = m8 ^ ((col & 1) << 3);
    *(half8*)&AL[col * MM + phys] = *(const half8*)&ATb[(size_t)n * MM + m8];
  }

  // ---- register cols: n = 64w+16+g and 64w+24+g (16 VGPRs, pinned)
  float rcw[16];
  {
    int n0 = 64 * w + 16 + g, n1 = 64 * w + 24 + g;
    f32x4 v0 = *(const f32x4*)&ATb[(size_t)n0 * MM + mb];
    f32x4 v1 = *(const f32x4*)&ATb[(size_t)n0 * MM + mb + 8];
    f32x4 v2 = *(const f32x4*)&ATb[(size_t)n1 * MM + mb];
    f32x4 v3 = *(const f32x4*)&ATb[(size_t)n1 * MM + mb + 8];
    rcw[0] = v0[0]; rcw[1] = v0[1]; rcw[2] = v0[2]; rcw[3] = v0[3];
    rcw[4] = v1[0]; rcw[5] = v1[1]; rcw[6] = v1[2]; rcw[7] = v1[3];
    rcw[8] = v2[0]; rcw[9] = v2[1]; rcw[10] = v2[2]; rcw[11] = v2[3];
    rcw[12] = v3[0]; rcw[13] = v3[1]; rcw[14] = v3[2]; rcw[15] = v3[3];
  }
#pragma unroll
  for (int k = 0; k < 16; ++k) asm volatile("" : "+v"(rcw[k]));

  // ---- z state in registers: 8 cols/group, all 8 lanes hold identical
  // copies (DPP butterfly sums are bit-identical across lanes).
  float zz[8];
#pragma unroll
  for (int k = 0; k < 8; ++k) zz[k] = 0.0f;

  __syncthreads();

  for (int it = 0; it < ITERS; ++it) {
    bool last = (it == ITERS - 1);

    // ---- issue streamed-col loads early (n = 64w+g, 64w+8+g)
    f32x4 sa0 = *(const f32x4*)&ATb[(size_t)(64 * w + g) * MM + mb];
    f32x4 sa1 = *(const f32x4*)&ATb[(size_t)(64 * w + g) * MM + mb + 8];
    f32x4 sb0 = *(const f32x4*)&ATb[(size_t)(64 * w + 8 + g) * MM + mb];
    f32x4 sb1 = *(const f32x4*)&ATb[(size_t)(64 * w + 8 + g) * MM + mb + 8];

    // ---- u = G * s  (8 threads per row, packed fp16 dot; DPP 8-lane reduce)
    {
      int j0 = 16 * sub;
      half8 sA = *(const half8*)&s_h[j0];
      half8 sB = *(const half8*)&s_h[j0 + 8];
      float up = 0.0f;
      up = __builtin_amdgcn_fdot2(__builtin_bit_cast(half2v, ghf[0]),
                                  __builtin_shufflevector(sA, sA, 0, 1), up, false);
      up = __builtin_amdgcn_fdot2(__builtin_bit_cast(half2v, ghf[1]),
                                  __builtin_shufflevector(sA, sA, 2, 3), up, false);
      up = __builtin_amdgcn_fdot2(__builtin_bit_cast(half2v, ghf[2]),
                                  __builtin_shufflevector(sA, sA, 4, 5), up, false);
      up = __builtin_amdgcn_fdot2(__builtin_bit_cast(half2v, ghf[3]),
                                  __builtin_shufflevector(sA, sA, 6, 7), up, false);
      up = __builtin_amdgcn_fdot2(__builtin_bit_cast(half2v, ghf[4]),
                                  __builtin_shufflevector(sB, sB, 0, 1), up, false);
      up = __builtin_amdgcn_fdot2(__builtin_bit_cast(half2v, ghf[5]),
                                  __builtin_shufflevector(sB, sB, 2, 3), up, false);
      up = __builtin_amdgcn_fdot2(__builtin_bit_cast(half2v, ghf[6]),
                                  __builtin_shufflevector(sB, sB, 4, 5), up, false);
      up = __builtin_amdgcn_fdot2(__builtin_bit_cast(half2v, ghf[7]),
                                  __builtin_shufflevector(sB, sB, 6, 7), up, false);
      up = dpp_add<0xB1>(up);
      up = dpp_add<0x4E>(up);
      up = dpp_add<0x141>(up);
      if (sub == 0) u_h[r] = (_Float16)up;
    }
    __syncthreads();
    half8 uA = *(const half8*)&u_h[mb];
    half8 uB = *(const half8*)&u_h[mb + 8];
    half2v u0 = __builtin_shufflevector(uA, uA, 0, 1);
    half2v u1 = __builtin_shufflevector(uA, uA, 2, 3);
    half2v u2 = __builtin_shufflevector(uA, uA, 4, 5);
    half2v u3 = __builtin_shufflevector(uA, uA, 6, 7);
    half2v u4 = __builtin_shufflevector(uB, uB, 0, 1);
    half2v u5 = __builtin_shufflevector(uB, uB, 2, 3);
    half2v u6 = __builtin_shufflevector(uB, uB, 4, 5);
    half2v u7 = __builtin_shufflevector(uB, uB, 6, 7);

    float t[16];
#pragma unroll
    for (int k = 0; k < 16; ++k) t[k] = 0.0f;

    // z passed BY VALUE, new z returned (no address-taken state).
    auto colstep = [&](half8 ha, half8 hb, int n, float zv) -> float {
      float cp = 0.0f;
      cp = __builtin_amdgcn_fdot2(__builtin_shufflevector(ha, ha, 0, 1), u0, cp, false);
      cp = __builtin_amdgcn_fdot2(__builtin_shufflevector(ha, ha, 2, 3), u1, cp, false);
      cp = __builtin_amdgcn_fdot2(__builtin_shufflevector(ha, ha, 4, 5), u2, cp, false);
      cp = __builtin_amdgcn_fdot2(__builtin_shufflevector(ha, ha, 6, 7), u3, cp, false);
      cp = __builtin_amdgcn_fdot2(__builtin_shufflevector(hb, hb, 0, 1), u4, cp, false);
      cp = __builtin_amdgcn_fdot2(__builtin_shufflevector(hb, hb, 2, 3), u5, cp, false);
      cp = __builtin_amdgcn_fdot2(__builtin_shufflevector(hb, hb, 4, 5), u6, cp, false);
      cp = __builtin_amdgcn_fdot2(__builtin_shufflevector(hb, hb, 6, 7), u7, cp, false);
      cp = dpp_add<0xB1>(cp);    // xor1
      cp = dpp_add<0x4E>(cp);    // xor2
      cp = dpp_add<0x141>(cp);   // half_mirror: 8-sum in all 8 lanes
      float2 tdi = tdi_sh[n];
      float td = tdi.x, di = tdi.y;
      float xm = zv - td, xp = zv + td;
      float xh = xm > 0.0f ? xm * di : (xp < 0.0f ? xp * di : 0.0f);
      if (!last) {
        float z1 = xh - cp;                     // z_{i+1}
        float xm1 = z1 - td, xp1 = z1 + td;
        float xh1 = xm1 > 0.0f ? xm1 * di : (xp1 < 0.0f ? xp1 * di : 0.0f);
        float y = 2.0f * xh1 - z1;              // y_{i+1}
        f32x4 wa = __builtin_bit_cast(f32x4, ha);
        f32x4 wb = __builtin_bit_cast(f32x4, hb);
#pragma unroll
        for (int i2 = 0; i2 < 4; ++i2) {
          asm("v_fma_mix_f32 %0, %1, %2, %0 op_sel_hi:[1,0,0]"
              : "+v"(t[2 * i2]) : "v"(wa[i2]), "v"(y));
          asm("v_fma_mix_f32 %0, %1, %2, %0 op_sel:[1,0,0] op_sel_hi:[1,0,0]"
              : "+v"(t[2 * i2 + 1]) : "v"(wa[i2]), "v"(y));
          asm("v_fma_mix_f32 %0, %1, %2, %0 op_sel_hi:[1,0,0]"
              : "+v"(t[8 + 2 * i2]) : "v"(wb[i2]), "v"(y));
          asm("v_fma_mix_f32 %0, %1, %2, %0 op_sel:[1,0,0] op_sel_hi:[1,0,0]"
              : "+v"(t[8 + 2 * i2 + 1]) : "v"(wb[i2]), "v"(y));
        }
        return z1;
      } else {
        float y = 2.0f * xh - zv;               // y_99 from z_99
        if (l8 == 0) z_sh[n] = y - cp;          // x_99 (output)
        return zv;
      }
    };

    // register cols, then LDS cols, then streamed (loads have arrived)
    {
      f32x4 ra = {rcw[0], rcw[1], rcw[2], rcw[3]};
      f32x4 rb = {rcw[4], rcw[5], rcw[6], rcw[7]};
      zz[0] = colstep(__builtin_bit_cast(half8, ra),
                      __builtin_bit_cast(half8, rb), 64 * w + 16 + g, zz[0]);
      f32x4 rc_ = {rcw[8], rcw[9], rcw[10], rcw[11]};
      f32x4 rd_ = {rcw[12], rcw[13], rcw[14], rcw[15]};
      zz[1] = colstep(__builtin_bit_cast(half8, rc_),
                      __builtin_bit_cast(half8, rd_), 64 * w + 24 + g, zz[1]);
    }
#pragma unroll
    for (int j = 0; j < 4; ++j) {
      const _Float16* ap = &AL[(32 * w + 8 * j + g) * MM];
      half8 ha = *(const half8*)&ap[mb + alsw];
      half8 hb = *(const half8*)&ap[mb + 8 - alsw];
      zz[2 + j] = colstep(ha, hb, 64 * w + 32 + 8 * j + g, zz[2 + j]);
    }
    zz[6] = colstep(__builtin_bit_cast(half8, sa0),
                    __builtin_bit_cast(half8, sa1), 64 * w + g, zz[6]);
    zz[7] = colstep(__builtin_bit_cast(half8, sb0),
                    __builtin_bit_cast(half8, sb1), 64 * w + 8 + g, zz[7]);

    if (!last) {
      // ---- cross-group: xor8 (DPP row_ror:8) + xor32 (shfl); xor16 skipped,
      // g==0 and g==2 lanes hold complementary partials -> 32 rows.
#pragma unroll
      for (int k = 0; k < 16; ++k) {
        t[k] = dpp_add<0x128>(t[k]);
        t[k] += __shfl_xor(t[k], 32);
      }
      if ((g & 5) == 0) {
        int row = 2 * w + (g >> 1);
#pragma unroll
        for (int s2 = 0; s2 < 4; ++s2) {
          f32x4 tv = {t[4 * s2], t[4 * s2 + 1], t[4 * s2 + 2], t[4 * s2 + 3]};
          *(f32x4*)&t_redW[row][mb + 4 * s2] = tv;
        }
      }
      __syncthreads();
      if (tid < MM) {
        float ssum = -b_sh[tid];
#pragma unroll
        for (int h = 0; h < 32; ++h) ssum += t_redW[h][tid];
        s_h[tid] = (_Float16)ssum;   // s = A*y - b for next pass's u
      }
      __syncthreads();
    }
  }

  __syncthreads();
  out[(size_t)b * NN + tid] = z_sh[tid];
}

// ---------------------------------------------------------------------------
extern "C" void kernel_launch(void* const* d_in, const int* in_sizes, int n_in,
                              void* d_out, int out_size, void* d_ws, size_t ws_size,
                              hipStream_t stream) {
  const float* A  = (const float*)d_in[0];  // (BS, M, N)
  const float* bv = (const float*)d_in[1];  // (BS, M)
  const float* D1 = (const float*)d_in[2];  // (BS, N)
  const float* D2 = (const float*)d_in[3];  // (BS, N)
  float* out = (float*)d_out;               // (BS, N)

  _Float16* ATh = (_Float16*)d_ws;                              // 67 MB
  float* G = (float*)((char*)d_ws + (size_t)BS * NN * MM * 2);  // 16.7 MB

  k_aat<<<BS, 512, 0, stream>>>(A, G, ATh);
  k_inv<<<BS, 512, 0, stream>>>(G);
  k_main<<<BS, 1024, 0, stream>>>(ATh, G, bv, D1, D2, out);
}

// Round 4
// 727.367 us; speedup vs baseline: 2.8630x; 1.2682x over previous
//
#include <hip/hip_runtime.h>
#include <math.h>

#define BS 256
#define MM 128
#define NN 1024
#define ITERS 100
#define ALPHA 0.1f
#define AST 129
#define IST 129
#define TRP 132

typedef _Float16 half8 __attribute__((ext_vector_type(8)));
typedef _Float16 half4 __attribute__((ext_vector_type(4)));
typedef _Float16 half2v __attribute__((ext_vector_type(2)));
typedef float f32x4 __attribute__((ext_vector_type(4)));

// Exact butterfly add via DPP (VALU pipe, no LDS). Controls:
//   0xB1 quad_perm xor1 | 0x4E quad_perm xor2 | 0x141 row_half_mirror (xor7
//   within 8) | 0x128 row_ror:8 (xor8 within 16-lane row)
template <int CTRL>
__device__ __forceinline__ float dpp_add(float x) {
  int xi = __builtin_bit_cast(int, x);
  int r = __builtin_amdgcn_update_dpp(xi, xi, CTRL, 0xf, 0xf, true);
  return x + __builtin_bit_cast(float, r);
}

// ---------------------------------------------------------------------------
// FULLY FUSED: AAT (split-fp16 MFMA) -> register-resident Gauss-Jordan
// inverse -> 100-iteration solver. One block per batch, 1024 threads.
// No cross-block dataflow exists in this problem, so the three former
// kernels collapse into sequential phases (G stays in LDS; only the fp16
// AT copy transits global, written+read by the SAME block -> L2-local).
__global__ __attribute__((amdgpu_waves_per_eu(4, 4)))
__launch_bounds__(1024) void k_fused(
    const float* __restrict__ A, const float* __restrict__ bvec,
    const float* __restrict__ D1, const float* __restrict__ D2,
    float* __restrict__ out, _Float16* __restrict__ ATh) {
  // Phase-1 staging + Msh alias phase-3's AL (max 131,840 B). Small solver
  // arrays stay separate __shared__ globals so hot-loop alias analysis is
  // exact. Total LDS = 160,000 B.
  union BigU {
    struct {
      float As[64 * AST];                      // 33,024
      __align__(16) _Float16 Thi[8][2][64][8]; // 16,384
      __align__(16) _Float16 Tlo[8][2][64][8]; // 16,384
      float Msh[MM * IST];                     // 66,048
    } p1;
    __align__(16) _Float16 AL[512 * MM];       // 131,072
  };
  __shared__ BigU bu;
  __shared__ float2 tdi_sh[NN];
  __shared__ float b_sh[MM];
  __shared__ __align__(16) _Float16 s_h[MM];
  __shared__ __align__(16) _Float16 u_h[MM];
  __shared__ __align__(16) float t_redW[32][TRP];
  __shared__ float fcol[2][MM];   // GJ ping-pong stash: col k of M^(k-1)
  __shared__ float frow[2][MM];   // GJ ping-pong stash: row k of M^(k-1)

  int b = blockIdx.x;
  int tid = threadIdx.x;
  const float* Ab = A + (size_t)b * MM * NN;
  _Float16* ATb = ATh + (size_t)b * NN * MM;

  // ================= PHASE 1: AAT via split-fp16 MFMA + ATh emission ======
  // hi/lo decomposition: a = hi + lo, keep hi*hi + hi*lo + lo*hi ->
  // fp32-equivalent accuracy. 16 waves, 2x2 16x16 tiles each.
  {
    float* As = bu.p1.As;
    auto& Thi = bu.p1.Thi;
    auto& Tlo = bu.p1.Tlo;
    int lane = tid & 63;
    int w16 = tid >> 6;    // 0..15
    int wr = w16 & 3;      // row strips {2wr, 2wr+1}
    int wc = w16 >> 2;     // col strips {2wc, 2wc+1}
    f32x4 acc[2][2];
#pragma unroll
    for (int i = 0; i < 2; ++i)
#pragma unroll
      for (int jj = 0; jj < 2; ++jj) acc[i][jj] = (f32x4){0.f, 0.f, 0.f, 0.f};

    for (int t = 0; t < 16; ++t) {
      int k0 = t * 64;
#pragma unroll
      for (int s = 0; s < 2; ++s) {
        int c = tid + 1024 * s;       // 0..2047
        int m = c >> 4;               // 0..127
        int q = c & 15;
        int kl = q * 4;               // 0..60
        float4 v = *(const float4*)&Ab[(size_t)m * NN + k0 + kl];
        As[(kl + 0) * AST + m] = v.x;
        As[(kl + 1) * AST + m] = v.y;
        As[(kl + 2) * AST + m] = v.z;
        As[(kl + 3) * AST + m] = v.w;
        _Float16 h0 = (_Float16)v.x, h1 = (_Float16)v.y;
        _Float16 h2 = (_Float16)v.z, h3 = (_Float16)v.w;
        half4 hv = {h0, h1, h2, h3};
        half4 lv = {(_Float16)(v.x - (float)h0), (_Float16)(v.y - (float)h1),
                    (_Float16)(v.z - (float)h2), (_Float16)(v.w - (float)h3)};
        int strip = m >> 4;
        int kc = kl >> 5;
        int ln = (m & 15) + (((kl & 31) >> 3) << 4);
        int j0 = kl & 7;
        *(half4*)&Thi[strip][kc][ln][j0] = hv;
        *(half4*)&Tlo[strip][kc][ln][j0] = lv;
      }
      __syncthreads();
      // emit fp16 AT k-slice (same conversion path as previous rounds)
#pragma unroll
      for (int s = 0; s < 4; ++s) {
        int idx = tid + 1024 * s;     // 0..4095
        int nl = idx >> 6;
        int mp = idx & 63;
        half2v hv;
        hv[0] = (_Float16)As[nl * AST + 2 * mp];
        hv[1] = (_Float16)As[nl * AST + 2 * mp + 1];
        *(half2v*)&ATb[(size_t)(k0 + nl) * MM + 2 * mp] = hv;
      }
#pragma unroll
      for (int kc = 0; kc < 2; ++kc) {
        half8 ahi[2], alo[2], bhi[2], blo[2];
#pragma unroll
        for (int i = 0; i < 2; ++i) {
          ahi[i] = *(const half8*)&Thi[2 * wr + i][kc][lane][0];
          alo[i] = *(const half8*)&Tlo[2 * wr + i][kc][lane][0];
          bhi[i] = *(const half8*)&Thi[2 * wc + i][kc][lane][0];
          blo[i] = *(const half8*)&Tlo[2 * wc + i][kc][lane][0];
        }
#pragma unroll
        for (int i = 0; i < 2; ++i)
#pragma unroll
          for (int jj = 0; jj < 2; ++jj) {
            acc[i][jj] = __builtin_amdgcn_mfma_f32_16x16x32_f16(
                ahi[i], bhi[jj], acc[i][jj], 0, 0, 0);
            acc[i][jj] = __builtin_amdgcn_mfma_f32_16x16x32_f16(
                ahi[i], blo[jj], acc[i][jj], 0, 0, 0);
            acc[i][jj] = __builtin_amdgcn_mfma_f32_16x16x32_f16(
                alo[i], bhi[jj], acc[i][jj], 0, 0, 0);
          }
      }
      __syncthreads();
    }
    // write C directly into LDS Msh (D layout: col=lane&15, row=4*(lane>>4)+r)
    float* Msh = bu.p1.Msh;
    int rbase = 4 * (lane >> 4), cbase = lane & 15;
#pragma unroll
    for (int i = 0; i < 2; ++i)
#pragma unroll
      for (int jj = 0; jj < 2; ++jj) {
        int r0 = (2 * wr + i) * 16 + rbase;
        int c0 = (2 * wc + jj) * 16 + cbase;
#pragma unroll
        for (int r_ = 0; r_ < 4; ++r_)
          Msh[(r0 + r_) * IST + c0] = acc[i][jj][r_];
      }
  }
  __syncthreads();

  // ================= PHASE 2: register-resident Gauss-Jordan inverse ======
  // Each thread owns 16 cells (rows i0..i0+15, col j) IN REGISTERS.
  // Pivot row/col come from 1KB ping-pong stashes written the step before
  // -> no LDS matrix read-modify-write traffic, ONE barrier per step.
  // k-loop unrolled x16 so the stash register index is compile-time.
  {
    float* Msh = bu.p1.Msh;
    int j = tid & 127;
    int i0 = (tid >> 7) * 16;
    float m[16];
#pragma unroll
    for (int ii = 0; ii < 16; ++ii) m[ii] = Msh[(i0 + ii) * IST + j];
    if (tid < MM) {
      fcol[0][tid] = Msh[tid * IST];   // col 0
      frow[0][tid] = Msh[tid];         // row 0
    }
    __syncthreads();
    int cur = 0;
    for (int kb = 0; kb < 8; ++kb) {
#pragma unroll
      for (int kq = 0; kq < 16; ++kq) {
        int k = kb * 16 + kq;
        float p = 1.0f / fcol[cur][k];
        float mkj = frow[cur][j];
        float fik[16];
#pragma unroll
        for (int ii = 0; ii < 16; ++ii) fik[ii] = fcol[cur][i0 + ii];
        float pmkj = p * mkj;
        bool pivslab = (i0 == kb * 16);
        if (j == k) {
#pragma unroll
          for (int ii = 0; ii < 16; ++ii) m[ii] = -p * fik[ii];
          if (pivslab) m[kq] = p;
        } else {
#pragma unroll
          for (int ii = 0; ii < 16; ++ii) m[ii] = fmaf(-fik[ii], pmkj, m[ii]);
          if (pivslab) m[kq] = pmkj;
        }
        int nxt = cur ^ 1;
        if (k < MM - 1) {
          if (j == k + 1) {
#pragma unroll
            for (int ii = 0; ii < 16; ++ii) fcol[nxt][i0 + ii] = m[ii];
          }
          if (i0 == ((k + 1) & ~15)) frow[nxt][j] = m[(kq + 1) & 15];
        }
        __syncthreads();
        cur = nxt;
      }
    }
#pragma unroll
    for (int ii = 0; ii < 16; ++ii) Msh[(i0 + ii) * IST + j] = m[ii];
  }
  __syncthreads();

  // ================= PHASE 3: persistent solver (round-3 structure) =======
  int sub = tid & 7, rrow = tid >> 3;
  float ghf[8];
  {
    const float* Msh = bu.p1.Msh;
#pragma unroll
    for (int s = 0; s < 4; ++s) {
      int base = rrow * IST + 16 * sub + 4 * s;
      float v0 = Msh[base + 0], v1 = Msh[base + 1];
      float v2 = Msh[base + 2], v3 = Msh[base + 3];
      half2v h0; h0[0] = (_Float16)v0; h0[1] = (_Float16)v1;
      half2v h1; h1[0] = (_Float16)v2; h1[1] = (_Float16)v3;
      ghf[2 * s + 0] = __builtin_bit_cast(float, h0);
      ghf[2 * s + 1] = __builtin_bit_cast(float, h1);
    }
  }
#pragma unroll
  for (int s = 0; s < 8; ++s) asm volatile("" : "+v"(ghf[s]));
  __syncthreads();   // Msh dead -> AL region free

  _Float16* AL = bu.AL;
  {
    float d1 = D1[(size_t)b * NN + tid];
    float d2 = D2[(size_t)b * NN + tid];
    float2 td2;
    td2.x = ALPHA * fabsf(d1);
    td2.y = 1.0f / (1.0f + 2.0f * ALPHA * d2 * d2);
    tdi_sh[tid] = td2;
  }
  if (tid < MM) {
    float bb = bvec[(size_t)b * MM + tid];
    b_sh[tid] = bb;
    s_h[tid] = (_Float16)(-bb);   // s_0 = A*y_0 - b = -b
  }

  int l8 = tid & 7;            // lane in 8-group
  int g = (tid >> 3) & 7;      // group within wave (8 groups)
  int w = tid >> 6;            // wave 0..15
  int mb = 16 * l8;            // m-slice base (16 elems/lane)
  int alsw = (g & 1) * 8;      // AL parity swizzle

  // ---- LDS cols: AL col c holds n = 64*(c>>5)+32+(c&31); 16B parity swizzle
#pragma unroll
  for (int i = 0; i < 8; ++i) {
    int c = tid + 1024 * i;
    int col = c >> 4;
    int m8 = (c & 15) * 8;
    int n = 32 * (col >> 5) + 32 + col;
    int phys = m8 ^ ((col & 1) << 3);
    *(half8*)&AL[col * MM + phys] = *(const half8*)&ATb[(size_t)n * MM + m8];
  }

  // ---- register cols: n = 64w+16+g and 64w+24+g (16 VGPRs, pinned)
  float rcw[16];
  {
    int n0 = 64 * w + 16 + g, n1 = 64 * w + 24 + g;
    f32x4 v0 = *(const f32x4*)&ATb[(size_t)n0 * MM + mb];
    f32x4 v1 = *(const f32x4*)&ATb[(size_t)n0 * MM + mb + 8];
    f32x4 v2 = *(const f32x4*)&ATb[(size_t)n1 * MM + mb];
    f32x4 v3 = *(const f32x4*)&ATb[(size_t)n1 * MM + mb + 8];
    rcw[0] = v0[0]; rcw[1] = v0[1]; rcw[2] = v0[2]; rcw[3] = v0[3];
    rcw[4] = v1[0]; rcw[5] = v1[1]; rcw[6] = v1[2]; rcw[7] = v1[3];
    rcw[8] = v2[0]; rcw[9] = v2[1]; rcw[10] = v2[2]; rcw[11] = v2[3];
    rcw[12] = v3[0]; rcw[13] = v3[1]; rcw[14] = v3[2]; rcw[15] = v3[3];
  }
#pragma unroll
  for (int k = 0; k < 16; ++k) asm volatile("" : "+v"(rcw[k]));

  // ---- z state in registers: 8 cols/group, replicated across the 8 lanes
  float zz[8];
#pragma unroll
  for (int k = 0; k < 8; ++k) zz[k] = 0.0f;

  __syncthreads();

  for (int it = 0; it < ITERS; ++it) {
    bool last = (it == ITERS - 1);

    // ---- issue streamed-col loads early (n = 64w+g, 64w+8+g)
    f32x4 sa0 = *(const f32x4*)&ATb[(size_t)(64 * w + g) * MM + mb];
    f32x4 sa1 = *(const f32x4*)&ATb[(size_t)(64 * w + g) * MM + mb + 8];
    f32x4 sb0 = *(const f32x4*)&ATb[(size_t)(64 * w + 8 + g) * MM + mb];
    f32x4 sb1 = *(const f32x4*)&ATb[(size_t)(64 * w + 8 + g) * MM + mb + 8];

    // ---- u = G * s  (8 threads per row, packed fp16 dot; DPP 8-lane reduce)
    {
      int j0 = 16 * sub;
      half8 sA = *(const half8*)&s_h[j0];
      half8 sB = *(const half8*)&s_h[j0 + 8];
      float up = 0.0f;
      up = __builtin_amdgcn_fdot2(__builtin_bit_cast(half2v, ghf[0]),
                                  __builtin_shufflevector(sA, sA, 0, 1), up, false);
      up = __builtin_amdgcn_fdot2(__builtin_bit_cast(half2v, ghf[1]),
                                  __builtin_shufflevector(sA, sA, 2, 3), up, false);
      up = __builtin_amdgcn_fdot2(__builtin_bit_cast(half2v, ghf[2]),
                                  __builtin_shufflevector(sA, sA, 4, 5), up, false);
      up = __builtin_amdgcn_fdot2(__builtin_bit_cast(half2v, ghf[3]),
                                  __builtin_shufflevector(sA, sA, 6, 7), up, false);
      up = __builtin_amdgcn_fdot2(__builtin_bit_cast(half2v, ghf[4]),
                                  __builtin_shufflevector(sB, sB, 0, 1), up, false);
      up = __builtin_amdgcn_fdot2(__builtin_bit_cast(half2v, ghf[5]),
                                  __builtin_shufflevector(sB, sB, 2, 3), up, false);
      up = __builtin_amdgcn_fdot2(__builtin_bit_cast(half2v, ghf[6]),
                                  __builtin_shufflevector(sB, sB, 4, 5), up, false);
      up = __builtin_amdgcn_fdot2(__builtin_bit_cast(half2v, ghf[7]),
                                  __builtin_shufflevector(sB, sB, 6, 7), up, false);
      up = dpp_add<0xB1>(up);
      up = dpp_add<0x4E>(up);
      up = dpp_add<0x141>(up);
      if (sub == 0) u_h[rrow] = (_Float16)up;
    }
    __syncthreads();
    half8 uA = *(const half8*)&u_h[mb];
    half8 uB = *(const half8*)&u_h[mb + 8];
    half2v u0 = __builtin_shufflevector(uA, uA, 0, 1);
    half2v u1 = __builtin_shufflevector(uA, uA, 2, 3);
    half2v u2 = __builtin_shufflevector(uA, uA, 4, 5);
    half2v u3 = __builtin_shufflevector(uA, uA, 6, 7);
    half2v u4 = __builtin_shufflevector(uB, uB, 0, 1);
    half2v u5 = __builtin_shufflevector(uB, uB, 2, 3);
    half2v u6 = __builtin_shufflevector(uB, uB, 4, 5);
    half2v u7 = __builtin_shufflevector(uB, uB, 6, 7);

    float t[16];
#pragma unroll
    for (int k = 0; k < 16; ++k) t[k] = 0.0f;

    // z passed BY VALUE, new z returned (no address-taken state).
    auto colstep = [&](half8 ha, half8 hb, int n, float zv) -> float {
      float cp = 0.0f;
      cp = __builtin_amdgcn_fdot2(__builtin_shufflevector(ha, ha, 0, 1), u0, cp, false);
      cp = __builtin_amdgcn_fdot2(__builtin_shufflevector(ha, ha, 2, 3), u1, cp, false);
      cp = __builtin_amdgcn_fdot2(__builtin_shufflevector(ha, ha, 4, 5), u2, cp, false);
      cp = __builtin_amdgcn_fdot2(__builtin_shufflevector(ha, ha, 6, 7), u3, cp, false);
      cp = __builtin_amdgcn_fdot2(__builtin_shufflevector(hb, hb, 0, 1), u4, cp, false);
      cp = __builtin_amdgcn_fdot2(__builtin_shufflevector(hb, hb, 2, 3), u5, cp, false);
      cp = __builtin_amdgcn_fdot2(__builtin_shufflevector(hb, hb, 4, 5), u6, cp, false);
      cp = __builtin_amdgcn_fdot2(__builtin_shufflevector(hb, hb, 6, 7), u7, cp, false);
      cp = dpp_add<0xB1>(cp);    // xor1
      cp = dpp_add<0x4E>(cp);    // xor2
      cp = dpp_add<0x141>(cp);   // half_mirror: 8-sum in all 8 lanes
      float2 tdi = tdi_sh[n];
      float td = tdi.x, di = tdi.y;
      float xm = zv - td, xp = zv + td;
      float xh = xm > 0.0f ? xm * di : (xp < 0.0f ? xp * di : 0.0f);
      if (!last) {
        float z1 = xh - cp;                     // z_{i+1}
        float xm1 = z1 - td, xp1 = z1 + td;
        float xh1 = xm1 > 0.0f ? xm1 * di : (xp1 < 0.0f ? xp1 * di : 0.0f);
        float y = 2.0f * xh1 - z1;              // y_{i+1}
        f32x4 wa = __builtin_bit_cast(f32x4, ha);
        f32x4 wb = __builtin_bit_cast(f32x4, hb);
#pragma unroll
        for (int i2 = 0; i2 < 4; ++i2) {
          asm("v_fma_mix_f32 %0, %1, %2, %0 op_sel_hi:[1,0,0]"
              : "+v"(t[2 * i2]) : "v"(wa[i2]), "v"(y));
          asm("v_fma_mix_f32 %0, %1, %2, %0 op_sel:[1,0,0] op_sel_hi:[1,0,0]"
              : "+v"(t[2 * i2 + 1]) : "v"(wa[i2]), "v"(y));
          asm("v_fma_mix_f32 %0, %1, %2, %0 op_sel_hi:[1,0,0]"
              : "+v"(t[8 + 2 * i2]) : "v"(wb[i2]), "v"(y));
          asm("v_fma_mix_f32 %0, %1, %2, %0 op_sel:[1,0,0] op_sel_hi:[1,0,0]"
              : "+v"(t[8 + 2 * i2 + 1]) : "v"(wb[i2]), "v"(y));
        }
        return z1;
      } else {
        float y = 2.0f * xh - zv;               // y_99 from z_99
        if (l8 == 0) out[(size_t)b * NN + n] = y - cp;   // x_99 direct
        return zv;
      }
    };

    // register cols, then LDS cols, then streamed (loads have arrived)
    {
      f32x4 ra = {rcw[0], rcw[1], rcw[2], rcw[3]};
      f32x4 rb = {rcw[4], rcw[5], rcw[6], rcw[7]};
      zz[0] = colstep(__builtin_bit_cast(half8, ra),
                      __builtin_bit_cast(half8, rb), 64 * w + 16 + g, zz[0]);
      f32x4 rc_ = {rcw[8], rcw[9], rcw[10], rcw[11]};
      f32x4 rd_ = {rcw[12], rcw[13], rcw[14], rcw[15]};
      zz[1] = colstep(__builtin_bit_cast(half8, rc_),
                      __builtin_bit_cast(half8, rd_), 64 * w + 24 + g, zz[1]);
    }
#pragma unroll
    for (int j = 0; j < 4; ++j) {
      const _Float16* ap = &AL[(32 * w + 8 * j + g) * MM];
      half8 ha = *(const half8*)&ap[mb + alsw];
      half8 hb = *(const half8*)&ap[mb + 8 - alsw];
      zz[2 + j] = colstep(ha, hb, 64 * w + 32 + 8 * j + g, zz[2 + j]);
    }
    zz[6] = colstep(__builtin_bit_cast(half8, sa0),
                    __builtin_bit_cast(half8, sa1), 64 * w + g, zz[6]);
    zz[7] = colstep(__builtin_bit_cast(half8, sb0),
                    __builtin_bit_cast(half8, sb1), 64 * w + 8 + g, zz[7]);

    if (!last) {
      // ---- cross-group: xor8 (DPP row_ror:8) + xor32 (shfl); xor16 skipped
      // (g==0 and g==2 hold complementary partials -> 32 rows)
#pragma unroll
      for (int k = 0; k < 16; ++k) {
        t[k] = dpp_add<0x128>(t[k]);
        t[k] += __shfl_xor(t[k], 32);
      }
      if ((g & 5) == 0) {
        int row = 2 * w + (g >> 1);
#pragma unroll
        for (int s2 = 0; s2 < 4; ++s2) {
          f32x4 tv = {t[4 * s2], t[4 * s2 + 1], t[4 * s2 + 2], t[4 * s2 + 3]};
          *(f32x4*)&t_redW[row][mb + 4 * s2] = tv;
        }
      }
      __syncthreads();
      if (tid < MM) {
        float ssum = -b_sh[tid];
#pragma unroll
        for (int h = 0; h < 32; ++h) ssum += t_redW[h][tid];
        s_h[tid] = (_Float16)ssum;   // s = A*y - b for next pass's u
      }
      __syncthreads();
    }
  }
}

// ---------------------------------------------------------------------------
extern "C" void kernel_launch(void* const* d_in, const int* in_sizes, int n_in,
                              void* d_out, int out_size, void* d_ws, size_t ws_size,
                              hipStream_t stream) {
  const float* A  = (const float*)d_in[0];  // (BS, M, N)
  const float* bv = (const float*)d_in[1];  // (BS, M)
  const float* D1 = (const float*)d_in[2];  // (BS, N)
  const float* D2 = (const float*)d_in[3];  // (BS, N)
  float* out = (float*)d_out;               // (BS, N)

  _Float16* ATh = (_Float16*)d_ws;          // 67 MB workspace (fp16 A^T)

  k_fused<<<BS, 1024, 0, stream>>>(A, bv, D1, D2, out, ATh);
}

// Round 5
// 713.664 us; speedup vs baseline: 2.9179x; 1.0192x over previous
//
#include <hip/hip_runtime.h>
#include <math.h>

#define BS 256
#define MM 128
#define NN 1024
#define ITERS 100
#define ALPHA 0.1f
#define AST 129
#define IST 129
#define TRP 132

typedef _Float16 half8 __attribute__((ext_vector_type(8)));
typedef _Float16 half4 __attribute__((ext_vector_type(4)));
typedef _Float16 half2v __attribute__((ext_vector_type(2)));
typedef float f32x4 __attribute__((ext_vector_type(4)));

// Exact butterfly add via DPP (VALU pipe, no LDS). Controls:
//   0xB1 quad_perm xor1 | 0x4E quad_perm xor2 | 0x141 row_half_mirror (xor7
//   within 8) | 0x128 row_ror:8 (xor8 within 16-lane row)
template <int CTRL>
__device__ __forceinline__ float dpp_add(float x) {
  int xi = __builtin_bit_cast(int, x);
  int r = __builtin_amdgcn_update_dpp(xi, xi, CTRL, 0xf, 0xf, true);
  return x + __builtin_bit_cast(float, r);
}

// ---------------------------------------------------------------------------
// PREP: AAT (split-fp16 MFMA, next-tile register prefetch) -> register-
// resident Gauss-Jordan inverse -> Gh (fp16, row-major, main's ghf layout).
// One block per batch, 1024 threads. Split from the solver so rocprof
// reports the two dispatch durations separately (phase attribution).
__global__ __attribute__((amdgpu_waves_per_eu(4, 4)))
__launch_bounds__(1024) void k_prep(const float* __restrict__ A,
                                    _Float16* __restrict__ ATh,
                                    _Float16* __restrict__ Gh) {
  __shared__ float As[64 * AST];                          // 33,024
  __shared__ __align__(16) _Float16 Thi[8][2][64][8];     // 16,384
  __shared__ __align__(16) _Float16 Tlo[8][2][64][8];     // 16,384
  __shared__ float Msh[MM * IST];                         // 66,048
  __shared__ float fcol[2][MM];                           // 1,024
  __shared__ float frow[2][MM];                           // 1,024

  int b = blockIdx.x;
  int tid = threadIdx.x;
  const float* Ab = A + (size_t)b * MM * NN;
  _Float16* ATb = ATh + (size_t)b * NN * MM;
  _Float16* Ghb = Gh + (size_t)b * MM * MM;

  // ================= PHASE 1: AAT via split-fp16 MFMA ====================
  // hi/lo decomposition: a = hi + lo, keep hi*hi + hi*lo + lo*hi ->
  // fp32-equivalent accuracy. 16 waves, 2x2 16x16 tiles each.
  // Next tile's global loads issue right after the stage barrier so HBM
  // latency hides under the ATh emit + MFMA (1 block/CU -> no TLP to hide it).
  {
    int lane = tid & 63;
    int w16 = tid >> 6;    // 0..15
    int wr = w16 & 3;      // row strips {2wr, 2wr+1}
    int wc = w16 >> 2;     // col strips {2wc, 2wc+1}
    int m0 = tid >> 4;     // staging chunk s=0: m 0..63
    int m1 = m0 + 64;      // staging chunk s=1: m 64..127
    int q0 = tid & 15;
    int kl = q0 * 4;       // local k 0..60
    int strip0 = m0 >> 4, strip1 = m1 >> 4;
    int kc_s = kl >> 5;
    int ln0 = (m0 & 15) + (((kl & 31) >> 3) << 4);
    int ln1 = (m1 & 15) + (((kl & 31) >> 3) << 4);
    int j0s = kl & 7;

    f32x4 acc[2][2];
#pragma unroll
    for (int i = 0; i < 2; ++i)
#pragma unroll
      for (int jj = 0; jj < 2; ++jj) acc[i][jj] = (f32x4){0.f, 0.f, 0.f, 0.f};

    auto stage = [&](int m, int strip, int ln, float4 v) {
      As[(kl + 0) * AST + m] = v.x;
      As[(kl + 1) * AST + m] = v.y;
      As[(kl + 2) * AST + m] = v.z;
      As[(kl + 3) * AST + m] = v.w;
      _Float16 h0 = (_Float16)v.x, h1 = (_Float16)v.y;
      _Float16 h2 = (_Float16)v.z, h3 = (_Float16)v.w;
      half4 hv = {h0, h1, h2, h3};
      half4 lv = {(_Float16)(v.x - (float)h0), (_Float16)(v.y - (float)h1),
                  (_Float16)(v.z - (float)h2), (_Float16)(v.w - (float)h3)};
      *(half4*)&Thi[strip][kc_s][ln][j0s] = hv;
      *(half4*)&Tlo[strip][kc_s][ln][j0s] = lv;
    };

    float4 va = *(const float4*)&Ab[(size_t)m0 * NN + kl];
    float4 vb = *(const float4*)&Ab[(size_t)m1 * NN + kl];

    for (int t = 0; t < 16; ++t) {
      int k0 = t * 64;
      stage(m0, strip0, ln0, va);
      stage(m1, strip1, ln1, vb);
      __syncthreads();
      // prefetch next tile (latency hides under emit + MFMA below)
      if (t < 15) {
        int k0n = k0 + 64;
        va = *(const float4*)&Ab[(size_t)m0 * NN + k0n + kl];
        vb = *(const float4*)&Ab[(size_t)m1 * NN + k0n + kl];
      }
      // emit fp16 AT k-slice (same conversion path as previous rounds)
#pragma unroll
      for (int s = 0; s < 4; ++s) {
        int idx = tid + 1024 * s;     // 0..4095
        int nl = idx >> 6;
        int mp = idx & 63;
        half2v hv;
        hv[0] = (_Float16)As[nl * AST + 2 * mp];
        hv[1] = (_Float16)As[nl * AST + 2 * mp + 1];
        *(half2v*)&ATb[(size_t)(k0 + nl) * MM + 2 * mp] = hv;
      }
#pragma unroll
      for (int kc = 0; kc < 2; ++kc) {
        half8 ahi[2], alo[2], bhi[2], blo[2];
#pragma unroll
        for (int i = 0; i < 2; ++i) {
          ahi[i] = *(const half8*)&Thi[2 * wr + i][kc][lane][0];
          alo[i] = *(const half8*)&Tlo[2 * wr + i][kc][lane][0];
          bhi[i] = *(const half8*)&Thi[2 * wc + i][kc][lane][0];
          blo[i] = *(const half8*)&Tlo[2 * wc + i][kc][lane][0];
        }
#pragma unroll
        for (int i = 0; i < 2; ++i)
#pragma unroll
          for (int jj = 0; jj < 2; ++jj) {
            acc[i][jj] = __builtin_amdgcn_mfma_f32_16x16x32_f16(
                ahi[i], bhi[jj], acc[i][jj], 0, 0, 0);
            acc[i][jj] = __builtin_amdgcn_mfma_f32_16x16x32_f16(
                ahi[i], blo[jj], acc[i][jj], 0, 0, 0);
            acc[i][jj] = __builtin_amdgcn_mfma_f32_16x16x32_f16(
                alo[i], bhi[jj], acc[i][jj], 0, 0, 0);
          }
      }
      __syncthreads();
    }
    // write C into LDS Msh (D layout: col=lane&15, row=4*(lane>>4)+r)
    int rbase = 4 * (lane >> 4), cbase = lane & 15;
#pragma unroll
    for (int i = 0; i < 2; ++i)
#pragma unroll
      for (int jj = 0; jj < 2; ++jj) {
        int r0 = (2 * wr + i) * 16 + rbase;
        int c0 = (2 * wc + jj) * 16 + cbase;
#pragma unroll
        for (int r_ = 0; r_ < 4; ++r_)
          Msh[(r0 + r_) * IST + c0] = acc[i][jj][r_];
      }
  }
  __syncthreads();

  // ================= PHASE 2: register-resident Gauss-Jordan inverse ======
  // Each thread owns 16 cells (rows i0..i0+15, col j) in registers; pivot
  // row/col come from 1KB ping-pong stashes -> one barrier per step.
  // Result exported straight to Gh as fp16 (identical cast to the old path).
  {
    int j = tid & 127;
    int i0 = (tid >> 7) * 16;
    float m[16];
#pragma unroll
    for (int ii = 0; ii < 16; ++ii) m[ii] = Msh[(i0 + ii) * IST + j];
    if (tid < MM) {
      fcol[0][tid] = Msh[tid * IST];   // col 0
      frow[0][tid] = Msh[tid];         // row 0
    }
    __syncthreads();
    int cur = 0;
    for (int kb = 0; kb < 8; ++kb) {
#pragma unroll
      for (int kq = 0; kq < 16; ++kq) {
        int k = kb * 16 + kq;
        float p = 1.0f / fcol[cur][k];
        float mkj = frow[cur][j];
        float fik[16];
#pragma unroll
        for (int ii = 0; ii < 16; ++ii) fik[ii] = fcol[cur][i0 + ii];
        float pmkj = p * mkj;
        bool pivslab = (i0 == kb * 16);
        if (j == k) {
#pragma unroll
          for (int ii = 0; ii < 16; ++ii) m[ii] = -p * fik[ii];
          if (pivslab) m[kq] = p;
        } else {
#pragma unroll
          for (int ii = 0; ii < 16; ++ii) m[ii] = fmaf(-fik[ii], pmkj, m[ii]);
          if (pivslab) m[kq] = pmkj;
        }
        int nxt = cur ^ 1;
        if (k < MM - 1) {
          if (j == k + 1) {
#pragma unroll
            for (int ii = 0; ii < 16; ++ii) fcol[nxt][i0 + ii] = m[ii];
          }
          if (i0 == ((k + 1) & ~15)) frow[nxt][j] = m[(kq + 1) & 15];
        }
        __syncthreads();
        cur = nxt;
      }
    }
    // export G as fp16 row-major (main reads rows as half8 pairs)
#pragma unroll
    for (int ii = 0; ii < 16; ++ii)
      Ghb[(size_t)(i0 + ii) * MM + j] = (_Float16)m[ii];
  }
}

// ---------------------------------------------------------------------------
// MAIN: persistent solver, one block per batch, 1024 threads (16 waves).
// Round-3's proven structure; ghf loads fp16 G directly (2x half8), output
// written straight from the last iteration's colstep.
__global__ __attribute__((amdgpu_waves_per_eu(4, 4)))
__launch_bounds__(1024) void k_main(
    const _Float16* __restrict__ AT, const _Float16* __restrict__ Gh,
    const float* __restrict__ bvec, const float* __restrict__ D1,
    const float* __restrict__ D2, float* __restrict__ out) {
  __shared__ __align__(16) _Float16 AL[512 * MM];   // 131,072
  __shared__ float2 tdi_sh[NN];                     // 8,192
  __shared__ float b_sh[MM];
  __shared__ __align__(16) _Float16 s_h[MM];
  __shared__ __align__(16) _Float16 u_h[MM];
  __shared__ __align__(16) float t_redW[32][TRP];   // 16,896

  int b = blockIdx.x;
  int tid = threadIdx.x;
  const _Float16* ATb = AT + (size_t)b * NN * MM;
  const _Float16* Ghb = Gh + (size_t)b * MM * MM;

  // ---- G fragment: 8 threads per row, 16 elems each, packed fp16 (8 VGPRs)
  int sub = tid & 7, rrow = tid >> 3;
  float ghf[8];
  {
    half8 g0 = *(const half8*)&Ghb[(size_t)rrow * MM + 16 * sub];
    half8 g1 = *(const half8*)&Ghb[(size_t)rrow * MM + 16 * sub + 8];
    f32x4 gA = __builtin_bit_cast(f32x4, g0);
    f32x4 gB = __builtin_bit_cast(f32x4, g1);
#pragma unroll
    for (int s = 0; s < 4; ++s) {
      ghf[s] = gA[s];
      ghf[4 + s] = gB[s];
    }
  }
#pragma unroll
  for (int s = 0; s < 8; ++s) asm volatile("" : "+v"(ghf[s]));
  {
    float d1 = D1[(size_t)b * NN + tid];
    float d2 = D2[(size_t)b * NN + tid];
    float2 td2;
    td2.x = ALPHA * fabsf(d1);
    td2.y = 1.0f / (1.0f + 2.0f * ALPHA * d2 * d2);
    tdi_sh[tid] = td2;
  }
  if (tid < MM) {
    float bb = bvec[(size_t)b * MM + tid];
    b_sh[tid] = bb;
    s_h[tid] = (_Float16)(-bb);   // s_0 = A*y_0 - b = -b
  }

  int l8 = tid & 7;            // lane in 8-group
  int g = (tid >> 3) & 7;      // group within wave (8 groups)
  int w = tid >> 6;            // wave 0..15
  int mb = 16 * l8;            // m-slice base (16 elems/lane)
  int alsw = (g & 1) * 8;      // AL parity swizzle

  // ---- LDS cols: AL col c holds n = 64*(c>>5)+32+(c&31); 16B parity swizzle
#pragma unroll
  for (int i = 0; i < 8; ++i) {
    int c = tid + 1024 * i;
    int col = c >> 4;
    int m8 = (c & 15) * 8;
    int n = 32 * (col >> 5) + 32 + col;
    int phys = m8 ^ ((col & 1) << 3);
    *(half8*)&AL[col * MM + phys] = *(const half8*)&ATb[(size_t)n * MM + m8];
  }

  // ---- register cols: n = 64w+16+g and 64w+24+g (16 VGPRs, pinned)
  float rcw[16];
  {
    int n0 = 64 * w + 16 + g, n1 = 64 * w + 24 + g;
    f32x4 v0 = *(const f32x4*)&ATb[(size_t)n0 * MM + mb];
    f32x4 v1 = *(const f32x4*)&ATb[(size_t)n0 * MM + mb + 8];
    f32x4 v2 = *(const f32x4*)&ATb[(size_t)n1 * MM + mb];
    f32x4 v3 = *(const f32x4*)&ATb[(size_t)n1 * MM + mb + 8];
    rcw[0] = v0[0]; rcw[1] = v0[1]; rcw[2] = v0[2]; rcw[3] = v0[3];
    rcw[4] = v1[0]; rcw[5] = v1[1]; rcw[6] = v1[2]; rcw[7] = v1[3];
    rcw[8] = v2[0]; rcw[9] = v2[1]; rcw[10] = v2[2]; rcw[11] = v2[3];
    rcw[12] = v3[0]; rcw[13] = v3[1]; rcw[14] = v3[2]; rcw[15] = v3[3];
  }
#pragma unroll
  for (int k = 0; k < 16; ++k) asm volatile("" : "+v"(rcw[k]));

  // ---- z state in registers: 8 cols/group, replicated across the 8 lanes
  float zz[8];
#pragma unroll
  for (int k = 0; k < 8; ++k) zz[k] = 0.0f;

  __syncthreads();

  for (int it = 0; it < ITERS; ++it) {
    bool last = (it == ITERS - 1);

    // ---- issue streamed-col loads early (n = 64w+g, 64w+8+g)
    f32x4 sa0 = *(const f32x4*)&ATb[(size_t)(64 * w + g) * MM + mb];
    f32x4 sa1 = *(const f32x4*)&ATb[(size_t)(64 * w + g) * MM + mb + 8];
    f32x4 sb0 = *(const f32x4*)&ATb[(size_t)(64 * w + 8 + g) * MM + mb];
    f32x4 sb1 = *(const f32x4*)&ATb[(size_t)(64 * w + 8 + g) * MM + mb + 8];

    // ---- u = G * s  (8 threads per row, packed fp16 dot; DPP 8-lane reduce)
    {
      int j0 = 16 * sub;
      half8 sA = *(const half8*)&s_h[j0];
      half8 sB = *(const half8*)&s_h[j0 + 8];
      float up = 0.0f;
      up = __builtin_amdgcn_fdot2(__builtin_bit_cast(half2v, ghf[0]),
                                  __builtin_shufflevector(sA, sA, 0, 1), up, false);
      up = __builtin_amdgcn_fdot2(__builtin_bit_cast(half2v, ghf[1]),
                                  __builtin_shufflevector(sA, sA, 2, 3), up, false);
      up = __builtin_amdgcn_fdot2(__builtin_bit_cast(half2v, ghf[2]),
                                  __builtin_shufflevector(sA, sA, 4, 5), up, false);
      up = __builtin_amdgcn_fdot2(__builtin_bit_cast(half2v, ghf[3]),
                                  __builtin_shufflevector(sA, sA, 6, 7), up, false);
      up = __builtin_amdgcn_fdot2(__builtin_bit_cast(half2v, ghf[4]),
                                  __builtin_shufflevector(sB, sB, 0, 1), up, false);
      up = __builtin_amdgcn_fdot2(__builtin_bit_cast(half2v, ghf[5]),
                                  __builtin_shufflevector(sB, sB, 2, 3), up, false);
      up = __builtin_amdgcn_fdot2(__builtin_bit_cast(half2v, ghf[6]),
                                  __builtin_shufflevector(sB, sB, 4, 5), up, false);
      up = __builtin_amdgcn_fdot2(__builtin_bit_cast(half2v, ghf[7]),
                                  __builtin_shufflevector(sB, sB, 6, 7), up, false);
      up = dpp_add<0xB1>(up);
      up = dpp_add<0x4E>(up);
      up = dpp_add<0x141>(up);
      if (sub == 0) u_h[rrow] = (_Float16)up;
    }
    __syncthreads();
    half8 uA = *(const half8*)&u_h[mb];
    half8 uB = *(const half8*)&u_h[mb + 8];
    half2v u0 = __builtin_shufflevector(uA, uA, 0, 1);
    half2v u1 = __builtin_shufflevector(uA, uA, 2, 3);
    half2v u2 = __builtin_shufflevector(uA, uA, 4, 5);
    half2v u3 = __builtin_shufflevector(uA, uA, 6, 7);
    half2v u4 = __builtin_shufflevector(uB, uB, 0, 1);
    half2v u5 = __builtin_shufflevector(uB, uB, 2, 3);
    half2v u6 = __builtin_shufflevector(uB, uB, 4, 5);
    half2v u7 = __builtin_shufflevector(uB, uB, 6, 7);

    float t[16];
#pragma unroll
    for (int k = 0; k < 16; ++k) t[k] = 0.0f;

    // z passed BY VALUE, new z returned (no address-taken state).
    auto colstep = [&](half8 ha, half8 hb, int n, float zv) -> float {
      float cp = 0.0f;
      cp = __builtin_amdgcn_fdot2(__builtin_shufflevector(ha, ha, 0, 1), u0, cp, false);
      cp = __builtin_amdgcn_fdot2(__builtin_shufflevector(ha, ha, 2, 3), u1, cp, false);
      cp = __builtin_amdgcn_fdot2(__builtin_shufflevector(ha, ha, 4, 5), u2, cp, false);
      cp = __builtin_amdgcn_fdot2(__builtin_shufflevector(ha, ha, 6, 7), u3, cp, false);
      cp = __builtin_amdgcn_fdot2(__builtin_shufflevector(hb, hb, 0, 1), u4, cp, false);
      cp = __builtin_amdgcn_fdot2(__builtin_shufflevector(hb, hb, 2, 3), u5, cp, false);
      cp = __builtin_amdgcn_fdot2(__builtin_shufflevector(hb, hb, 4, 5), u6, cp, false);
      cp = __builtin_amdgcn_fdot2(__builtin_shufflevector(hb, hb, 6, 7), u7, cp, false);
      cp = dpp_add<0xB1>(cp);    // xor1
      cp = dpp_add<0x4E>(cp);    // xor2
      cp = dpp_add<0x141>(cp);   // half_mirror: 8-sum in all 8 lanes
      float2 tdi = tdi_sh[n];
      float td = tdi.x, di = tdi.y;
      float xm = zv - td, xp = zv + td;
      float xh = xm > 0.0f ? xm * di : (xp < 0.0f ? xp * di : 0.0f);
      if (!last) {
        float z1 = xh - cp;                     // z_{i+1}
        float xm1 = z1 - td, xp1 = z1 + td;
        float xh1 = xm1 > 0.0f ? xm1 * di : (xp1 < 0.0f ? xp1 * di : 0.0f);
        float y = 2.0f * xh1 - z1;              // y_{i+1}
        f32x4 wa = __builtin_bit_cast(f32x4, ha);
        f32x4 wb = __builtin_bit_cast(f32x4, hb);
#pragma unroll
        for (int i2 = 0; i2 < 4; ++i2) {
          asm("v_fma_mix_f32 %0, %1, %2, %0 op_sel_hi:[1,0,0]"
              : "+v"(t[2 * i2]) : "v"(wa[i2]), "v"(y));
          asm("v_fma_mix_f32 %0, %1, %2, %0 op_sel:[1,0,0] op_sel_hi:[1,0,0]"
              : "+v"(t[2 * i2 + 1]) : "v"(wa[i2]), "v"(y));
          asm("v_fma_mix_f32 %0, %1, %2, %0 op_sel_hi:[1,0,0]"
              : "+v"(t[8 + 2 * i2]) : "v"(wb[i2]), "v"(y));
          asm("v_fma_mix_f32 %0, %1, %2, %0 op_sel:[1,0,0] op_sel_hi:[1,0,0]"
              : "+v"(t[8 + 2 * i2 + 1]) : "v"(wb[i2]), "v"(y));
        }
        return z1;
      } else {
        float y = 2.0f * xh - zv;               // y_99 from z_99
        if (l8 == 0) out[(size_t)b * NN + n] = y - cp;   // x_99 direct
        return zv;
      }
    };

    // register cols, then LDS cols, then streamed (loads have arrived)
    {
      f32x4 ra = {rcw[0], rcw[1], rcw[2], rcw[3]};
      f32x4 rb = {rcw[4], rcw[5], rcw[6], rcw[7]};
      zz[0] = colstep(__builtin_bit_cast(half8, ra),
                      __builtin_bit_cast(half8, rb), 64 * w + 16 + g, zz[0]);
      f32x4 rc_ = {rcw[8], rcw[9], rcw[10], rcw[11]};
      f32x4 rd_ = {rcw[12], rcw[13], rcw[14], rcw[15]};
      zz[1] = colstep(__builtin_bit_cast(half8, rc_),
                      __builtin_bit_cast(half8, rd_), 64 * w + 24 + g, zz[1]);
    }
#pragma unroll
    for (int j = 0; j < 4; ++j) {
      const _Float16* ap = &AL[(32 * w + 8 * j + g) * MM];
      half8 ha = *(const half8*)&ap[mb + alsw];
      half8 hb = *(const half8*)&ap[mb + 8 - alsw];
      zz[2 + j] = colstep(ha, hb, 64 * w + 32 + 8 * j + g, zz[2 + j]);
    }
    zz[6] = colstep(__builtin_bit_cast(half8, sa0),
                    __builtin_bit_cast(half8, sa1), 64 * w + g, zz[6]);
    zz[7] = colstep(__builtin_bit_cast(half8, sb0),
                    __builtin_bit_cast(half8, sb1), 64 * w + 8 + g, zz[7]);

    if (!last) {
      // ---- cross-group: xor8 (DPP row_ror:8) + xor32 (shfl); xor16 skipped
      // (g==0 and g==2 hold complementary partials -> 32 rows)
#pragma unroll
      for (int k = 0; k < 16; ++k) {
        t[k] = dpp_add<0x128>(t[k]);
        t[k] += __shfl_xor(t[k], 32);
      }
      if ((g & 5) == 0) {
        int row = 2 * w + (g >> 1);
#pragma unroll
        for (int s2 = 0; s2 < 4; ++s2) {
          f32x4 tv = {t[4 * s2], t[4 * s2 + 1], t[4 * s2 + 2], t[4 * s2 + 3]};
          *(f32x4*)&t_redW[row][mb + 4 * s2] = tv;
        }
      }
      __syncthreads();
      if (tid < MM) {
        float ssum = -b_sh[tid];
#pragma unroll
        for (int h = 0; h < 32; ++h) ssum += t_redW[h][tid];
        s_h[tid] = (_Float16)ssum;   // s = A*y - b for next pass's u
      }
      __syncthreads();
    }
  }
}

// ---------------------------------------------------------------------------
extern "C" void kernel_launch(void* const* d_in, const int* in_sizes, int n_in,
                              void* d_out, int out_size, void* d_ws, size_t ws_size,
                              hipStream_t stream) {
  const float* A  = (const float*)d_in[0];  // (BS, M, N)
  const float* bv = (const float*)d_in[1];  // (BS, M)
  const float* D1 = (const float*)d_in[2];  // (BS, N)
  const float* D2 = (const float*)d_in[3];  // (BS, N)
  float* out = (float*)d_out;               // (BS, N)

  _Float16* ATh = (_Float16*)d_ws;                              // 67 MB
  _Float16* Gh = (_Float16*)((char*)d_ws + (size_t)BS * NN * MM * 2);  // 8.4 MB

  k_prep<<<BS, 1024, 0, stream>>>(A, ATh, Gh);
  k_main<<<BS, 1024, 0, stream>>>(ATh, Gh, bv, D1, D2, out);
}